// Round 7
// baseline (325.824 us; speedup 1.0000x reference)
//
#include <hip/hip_runtime.h>
#include <math.h>

#define NEG_SLOPE 0.2f
#define EPS 1e-16f

__device__ inline float leaky(float v) {
    return v >= 0.0f ? v : NEG_SLOPE * v;
}

// pack two floats into bf16x2 (RNE), low half = first arg
__device__ inline unsigned bf16pack2(float a, float b) {
    unsigned ua = __float_as_uint(a);
    unsigned ub = __float_as_uint(b);
    ua = (ua + 0x7FFFu + ((ua >> 16) & 1u)) >> 16;
    ub = (ub + 0x7FFFu + ((ub >> 16) & 1u)) >> 16;
    return ua | (ub << 16);
}

__device__ inline float bf16lo(unsigned u) { return __uint_as_float(u << 16); }
__device__ inline float bf16hi(unsigned u) { return __uint_as_float(u & 0xFFFF0000u); }

// ================= bucket-binned CSR build =================
// Buckets of 256 dst nodes. Packed binned entry: (src << 8) | (dst & 255).
// Requires src < 2^24 and nbuckets <= 512 (N <= 131072).

// per-block LDS-aggregated bucket histogram over all T = E+N entries
__global__ __launch_bounds__(256) void k_binhist(const int* __restrict__ ei, int* __restrict__ bhist,
                                                 int E, int N) {
    __shared__ int sh[512];
    int tid = threadIdx.x;
    sh[tid] = 0; sh[tid + 256] = 0;
    __syncthreads();
    int T = E + N;
    int stride = gridDim.x * 256;
    for (int t = blockIdx.x * 256 + tid; t < T; t += stride) {
        int d = (t < E) ? ei[E + t] : (t - E);
        atomicAdd(&sh[d >> 8], 1);
    }
    __syncthreads();
    int c0 = sh[tid];       if (c0) atomicAdd(&bhist[tid], c0);
    int c1 = sh[tid + 256]; if (c1) atomicAdd(&bhist[tid + 256], c1);
}

// one-block exclusive scan of bucket counts -> bucketptr, bcursor; rowptr[N]=T
__global__ __launch_bounds__(512) void k_binscan(const int* __restrict__ bhist,
                                                 int* __restrict__ bucketptr,
                                                 int* __restrict__ bcursor,
                                                 int* __restrict__ rowptr,
                                                 int nb, int N, int T) {
    __shared__ int s[512];
    int tid = threadIdx.x;
    int v = (tid < nb) ? bhist[tid] : 0;
    s[tid] = v;
    __syncthreads();
#pragma unroll
    for (int off = 1; off < 512; off <<= 1) {
        int t = (tid >= off) ? s[tid - off] : 0;
        __syncthreads();
        s[tid] += t;
        __syncthreads();
    }
    int excl = s[tid] - v;
    if (tid < nb) { bucketptr[tid] = excl; bcursor[tid] = excl; }
    else          { bcursor[tid] = 0; }
    if (tid == 0) { bucketptr[nb] = T; rowptr[N] = T; }
}

// bin edges into bucket-contiguous regions (one atomic reservation per
// bucket per block; packed writes into reserved runs -> L2-coalesced).
#define BF_CHUNK 8192
__global__ __launch_bounds__(512) void k_binfill(const int* __restrict__ ei,
                                                 int* __restrict__ bcursor,
                                                 unsigned* __restrict__ binned,
                                                 int E, int N) {
    __shared__ int h[512], lc[512], gb[512];
    int tid = threadIdx.x;
    int T = E + N;
    int base = blockIdx.x * BF_CHUNK;
    int n = T - base; if (n > BF_CHUNK) n = BF_CHUNK;
    h[tid] = 0; lc[tid] = 0;
    __syncthreads();
    for (int i = tid; i < n; i += 512) {
        int t = base + i;
        int d = (t < E) ? ei[E + t] : (t - E);
        atomicAdd(&h[d >> 8], 1);
    }
    __syncthreads();
    if (h[tid] > 0) gb[tid] = atomicAdd(&bcursor[tid], h[tid]);
    __syncthreads();
    for (int i = tid; i < n; i += 512) {
        int t = base + i;
        int s, d;
        if (t < E) { s = ei[t]; d = ei[E + t]; } else { s = d = t - E; }
        int b = d >> 8;
        int slot = atomicAdd(&lc[b], 1);
        binned[gb[b] + slot] = ((unsigned)s << 8) | (unsigned)(d & 255);
    }
}

// ---------------- fat kernel: bucketfill (blocks < NB) + gemm1 (rest) ------
__global__ __launch_bounds__(256) void k_bucketfill_gemm1(
        const unsigned* __restrict__ binned, const int* __restrict__ bucketptr,
        int* __restrict__ rowptr, int* __restrict__ col,
        const float* __restrict__ x, const float* __restrict__ W1,
        const float* __restrict__ a_src, const float* __restrict__ a_dst,
        unsigned* __restrict__ h1bf, float* __restrict__ as1,
        float* __restrict__ ad1, int N, int nbuckets) {
    __shared__ float smem[64 * 128 + 32 * 64];   // 40 KB, aliased by role
    int tid = threadIdx.x;

    if ((int)blockIdx.x < nbuckets) {
        // ---- bucketfill role (256 threads) ----
        int* h  = (int*)smem;
        int* o  = h + 256;
        int* lc = o + 256;
        int b = blockIdx.x;
        int gs = bucketptr[b], ge = bucketptr[b + 1];
        h[tid] = 0; lc[tid] = 0;
        __syncthreads();
        for (int j = gs + tid; j < ge; j += 256)
            atomicAdd(&h[binned[j] & 255], 1);
        __syncthreads();
        int v = h[tid];
        o[tid] = v;
        __syncthreads();
#pragma unroll
        for (int off = 1; off < 256; off <<= 1) {
            int t = (tid >= off) ? o[tid - off] : 0;
            __syncthreads();
            o[tid] += t;
            __syncthreads();
        }
        int excl = o[tid] - v;
        int dst0 = b << 8;
        if (dst0 + tid < N) rowptr[dst0 + tid] = gs + excl;
        o[tid] = excl;
        __syncthreads();
        for (int j = gs + tid; j < ge; j += 256) {
            unsigned pv = binned[j];
            int d = pv & 255;
            int s = (int)(pv >> 8);
            int slot = atomicAdd(&lc[d], 1);
            col[gs + o[d] + slot] = s;
        }
        return;
    }

    // ---- gemm1 role ----
    float* sW = smem;                 // [64][128]
    float* sX = smem + 64 * 128;      // [32][64]
    int block_r0 = ((int)blockIdx.x - nbuckets) * 32;

    {
        float4* dst = (float4*)sW;
        const float4* srcp = (const float4*)W1;
#pragma unroll
        for (int i = 0; i < 8; ++i) dst[tid + 256 * i] = srcp[tid + 256 * i];
    }
    {
        float4* dst = (float4*)sX;
#pragma unroll
        for (int i = 0; i < 2; ++i) {
            int idx = tid + 256 * i;
            int r = idx >> 4;            // 0..31
            int c = idx & 15;            // float4 within row
            int gr = min(block_r0 + r, N - 1);
            dst[idx] = ((const float4*)(x + (size_t)gr * 64))[c];
        }
    }
    __syncthreads();

    int c4 = tid & 31;             // col quad 0..31
    int rq = tid >> 5;             // row quad 0..7
    int r0 = block_r0 + rq * 4;
    const float4* wS = (const float4*)sW;   // [64][32]
    const float4* xS = (const float4*)sX;   // [32][16]

    float4 acc0 = {0,0,0,0}, acc1 = {0,0,0,0}, acc2 = {0,0,0,0}, acc3 = {0,0,0,0};
#pragma unroll 2
    for (int k4 = 0; k4 < 16; ++k4) {
        float4 xa = xS[(rq * 4 + 0) * 16 + k4];
        float4 xb = xS[(rq * 4 + 1) * 16 + k4];
        float4 xc = xS[(rq * 4 + 2) * 16 + k4];
        float4 xd = xS[(rq * 4 + 3) * 16 + k4];
        float4 w0 = wS[(k4 * 4 + 0) * 32 + c4];
        float4 w1 = wS[(k4 * 4 + 1) * 32 + c4];
        float4 w2 = wS[(k4 * 4 + 2) * 32 + c4];
        float4 w3 = wS[(k4 * 4 + 3) * 32 + c4];
        acc0.x += xa.x*w0.x + xa.y*w1.x + xa.z*w2.x + xa.w*w3.x;
        acc0.y += xa.x*w0.y + xa.y*w1.y + xa.z*w2.y + xa.w*w3.y;
        acc0.z += xa.x*w0.z + xa.y*w1.z + xa.z*w2.z + xa.w*w3.z;
        acc0.w += xa.x*w0.w + xa.y*w1.w + xa.z*w2.w + xa.w*w3.w;
        acc1.x += xb.x*w0.x + xb.y*w1.x + xb.z*w2.x + xb.w*w3.x;
        acc1.y += xb.x*w0.y + xb.y*w1.y + xb.z*w2.y + xb.w*w3.y;
        acc1.z += xb.x*w0.z + xb.y*w1.z + xb.z*w2.z + xb.w*w3.z;
        acc1.w += xb.x*w0.w + xb.y*w1.w + xb.z*w2.w + xb.w*w3.w;
        acc2.x += xc.x*w0.x + xc.y*w1.x + xc.z*w2.x + xc.w*w3.x;
        acc2.y += xc.x*w0.y + xc.y*w1.y + xc.z*w2.y + xc.w*w3.y;
        acc2.z += xc.x*w0.z + xc.y*w1.z + xc.z*w2.z + xc.w*w3.z;
        acc2.w += xc.x*w0.w + xc.y*w1.w + xc.z*w2.w + xc.w*w3.w;
        acc3.x += xd.x*w0.x + xd.y*w1.x + xd.z*w2.x + xd.w*w3.x;
        acc3.y += xd.x*w0.y + xd.y*w1.y + xd.z*w2.y + xd.w*w3.y;
        acc3.z += xd.x*w0.z + xd.y*w1.z + xd.z*w2.z + xd.w*w3.z;
        acc3.w += xd.x*w0.w + xd.y*w1.w + xd.z*w2.w + xd.w*w3.w;
    }

    uint2 p0 = { bf16pack2(acc0.x, acc0.y), bf16pack2(acc0.z, acc0.w) };
    uint2 p1 = { bf16pack2(acc1.x, acc1.y), bf16pack2(acc1.z, acc1.w) };
    uint2 p2 = { bf16pack2(acc2.x, acc2.y), bf16pack2(acc2.z, acc2.w) };
    uint2 p3 = { bf16pack2(acc3.x, acc3.y), bf16pack2(acc3.z, acc3.w) };
    uint2* hb = (uint2*)h1bf;
    if (r0 + 0 < N) hb[(size_t)(r0 + 0) * 32 + c4] = p0;
    if (r0 + 1 < N) hb[(size_t)(r0 + 1) * 32 + c4] = p1;
    if (r0 + 2 < N) hb[(size_t)(r0 + 2) * 32 + c4] = p2;
    if (r0 + 3 < N) hb[(size_t)(r0 + 3) * 32 + c4] = p3;

    float4 av = ((const float4*)a_src)[c4];
    float4 dv = ((const float4*)a_dst)[c4];
    float s0 = acc0.x*av.x + acc0.y*av.y + acc0.z*av.z + acc0.w*av.w;
    float s1 = acc1.x*av.x + acc1.y*av.y + acc1.z*av.z + acc1.w*av.w;
    float s2 = acc2.x*av.x + acc2.y*av.y + acc2.z*av.z + acc2.w*av.w;
    float s3 = acc3.x*av.x + acc3.y*av.y + acc3.z*av.z + acc3.w*av.w;
    float d0 = acc0.x*dv.x + acc0.y*dv.y + acc0.z*dv.z + acc0.w*dv.w;
    float d1 = acc1.x*dv.x + acc1.y*dv.y + acc1.z*dv.z + acc1.w*dv.w;
    float d2 = acc2.x*dv.x + acc2.y*dv.y + acc2.z*dv.z + acc2.w*dv.w;
    float d3 = acc3.x*dv.x + acc3.y*dv.y + acc3.z*dv.z + acc3.w*dv.w;
#pragma unroll
    for (int off = 1; off < 8; off <<= 1) {
        s0 += __shfl_xor(s0, off); s1 += __shfl_xor(s1, off);
        s2 += __shfl_xor(s2, off); s3 += __shfl_xor(s3, off);
        d0 += __shfl_xor(d0, off); d1 += __shfl_xor(d1, off);
        d2 += __shfl_xor(d2, off); d3 += __shfl_xor(d3, off);
    }
    if ((c4 & 7) == 0) {
        int h = c4 >> 3;
        if (r0 + 0 < N) { as1[(r0 + 0) * 4 + h] = s0; ad1[(r0 + 0) * 4 + h] = d0; }
        if (r0 + 1 < N) { as1[(r0 + 1) * 4 + h] = s1; ad1[(r0 + 1) * 4 + h] = d1; }
        if (r0 + 2 < N) { as1[(r0 + 2) * 4 + h] = s2; ad1[(r0 + 2) * 4 + h] = d2; }
        if (r0 + 3 < N) { as1[(r0 + 3) * 4 + h] = s3; ad1[(r0 + 3) * 4 + h] = d3; }
    }
}

// ---------------- layer 1 fused gather -------------------------------------
// Fast path (deg <= 64, ~all nodes): single load of col+as1, logits in
// registers, wave-max, exp from registers (no second gather), one LDS sync.
// Phase C: 16 edges/iter, FOUR independent uint4 gathers per lane.
__global__ __launch_bounds__(256) void k_gather1(const int* __restrict__ rowptr,
                                                 const int* __restrict__ col,
                                                 const float* __restrict__ as1,
                                                 const float* __restrict__ ad1,
                                                 const unsigned* __restrict__ h1bf,
                                                 const float* __restrict__ b1,
                                                 float* __restrict__ out1, int N) {
    __shared__ float s_ex[4][64 * 4];   // [wave][edge*4+head]
    __shared__ int   s_src[4][64];      // [wave][edge]
    int tid = threadIdx.x;
    int wv = tid >> 6;
    int lane = tid & 63;
    int dst = blockIdx.x * 4 + wv;
    if (dst >= N) return;
    int start = rowptr[dst], end = rowptr[dst + 1];
    int deg = end - start;
    float4 ad = *(const float4*)(ad1 + (size_t)dst * 4);

    int sub = lane >> 4;           // edge slot 0..3
    int fl = lane & 15;            // uint4 index (features fl*8 .. fl*8+7)
    int hh = fl >> 2;              // head of this lane's features
    const uint4* hb4 = (const uint4*)h1bf;
    float* exw = s_ex[wv];
    int* srw = s_src[wv];

    float d0 = 0, d1 = 0, d2 = 0, d3 = 0;            // softmax denominators
    float4 accA = {0,0,0,0}, accB = {0,0,0,0};       // 8 features per lane

    if (deg <= 64) {
        // ---------------- single-chunk fast path ----------------
        int nedge = deg;
        float l0 = -INFINITY, l1 = -INFINITY, l2 = -INFINITY, l3 = -INFINITY;
        int src = 0;
        if (lane < nedge) {
            src = col[start + lane];
            float4 a = *(const float4*)(as1 + (size_t)src * 4);
            l0 = leaky(a.x + ad.x);
            l1 = leaky(a.y + ad.y);
            l2 = leaky(a.z + ad.z);
            l3 = leaky(a.w + ad.w);
        }
        float m0 = l0, m1 = l1, m2 = l2, m3 = l3;
#pragma unroll
        for (int off = 32; off; off >>= 1) {
            m0 = fmaxf(m0, __shfl_xor(m0, off));
            m1 = fmaxf(m1, __shfl_xor(m1, off));
            m2 = fmaxf(m2, __shfl_xor(m2, off));
            m3 = fmaxf(m3, __shfl_xor(m3, off));
        }
        // exp from register logits (lane >= nedge: l=-inf -> e=0)
        float e0 = __expf(l0 - m0);
        float e1 = __expf(l1 - m1);
        float e2 = __expf(l2 - m2);
        float e3 = __expf(l3 - m3);
        d0 = e0; d1 = e1; d2 = e2; d3 = e3;
        srw[lane] = src;
        float4 ev = {e0, e1, e2, e3};
        *(float4*)(exw + lane * 4) = ev;
        asm volatile("s_waitcnt lgkmcnt(0)" ::: "memory");  // writes visible wave-wide
        // phase C: 16 edges/iter, 4 independent gathers/lane (pads: ex=0)
        for (int e = 0; e < nedge; e += 16) {
            int ea = e + sub, eb = e + 4 + sub, ec = e + 8 + sub, ed = e + 12 + sub;
            int sa = srw[ea], sb = srw[eb], sc = srw[ec], sd = srw[ed];
            float xa = exw[ea * 4 + hh];
            float xb = exw[eb * 4 + hh];
            float xc = exw[ec * 4 + hh];
            float xd = exw[ed * 4 + hh];
            uint4 ua = hb4[(size_t)sa * 16 + fl];
            uint4 ub = hb4[(size_t)sb * 16 + fl];
            uint4 uc = hb4[(size_t)sc * 16 + fl];
            uint4 ud = hb4[(size_t)sd * 16 + fl];
            accA.x += xa * bf16lo(ua.x) + xb * bf16lo(ub.x) + xc * bf16lo(uc.x) + xd * bf16lo(ud.x);
            accA.y += xa * bf16hi(ua.x) + xb * bf16hi(ub.x) + xc * bf16hi(uc.x) + xd * bf16hi(ud.x);
            accA.z += xa * bf16lo(ua.y) + xb * bf16lo(ub.y) + xc * bf16lo(uc.y) + xd * bf16lo(ud.y);
            accA.w += xa * bf16hi(ua.y) + xb * bf16hi(ub.y) + xc * bf16hi(uc.y) + xd * bf16hi(ud.y);
            accB.x += xa * bf16lo(ua.z) + xb * bf16lo(ub.z) + xc * bf16lo(uc.z) + xd * bf16lo(ud.z);
            accB.y += xa * bf16hi(ua.z) + xb * bf16hi(ub.z) + xc * bf16hi(uc.z) + xd * bf16hi(ud.z);
            accB.z += xa * bf16lo(ua.w) + xb * bf16lo(ub.w) + xc * bf16lo(uc.w) + xd * bf16lo(ud.w);
            accB.w += xa * bf16hi(ua.w) + xb * bf16hi(ub.w) + xc * bf16hi(uc.w) + xd * bf16hi(ud.w);
        }
    } else {
        // ---------------- multi-chunk two-pass path (rare) ----------------
        float m0 = -INFINITY, m1 = -INFINITY, m2 = -INFINITY, m3 = -INFINITY;
        for (int j = start + lane; j < end; j += 64) {
            int src = col[j];
            float4 a = *(const float4*)(as1 + (size_t)src * 4);
            m0 = fmaxf(m0, leaky(a.x + ad.x));
            m1 = fmaxf(m1, leaky(a.y + ad.y));
            m2 = fmaxf(m2, leaky(a.z + ad.z));
            m3 = fmaxf(m3, leaky(a.w + ad.w));
        }
#pragma unroll
        for (int off = 32; off; off >>= 1) {
            m0 = fmaxf(m0, __shfl_xor(m0, off));
            m1 = fmaxf(m1, __shfl_xor(m1, off));
            m2 = fmaxf(m2, __shfl_xor(m2, off));
            m3 = fmaxf(m3, __shfl_xor(m3, off));
        }

        for (int base = start; base < end; base += 64) {
            int nedge = end - base; if (nedge > 64) nedge = 64;
            float e0 = 0, e1 = 0, e2 = 0, e3 = 0;
            int src = 0;
            if (lane < nedge) {
                src = col[base + lane];
                float4 a = *(const float4*)(as1 + (size_t)src * 4);
                e0 = __expf(leaky(a.x + ad.x) - m0);
                e1 = __expf(leaky(a.y + ad.y) - m1);
                e2 = __expf(leaky(a.z + ad.z) - m2);
                e3 = __expf(leaky(a.w + ad.w) - m3);
                d0 += e0; d1 += e1; d2 += e2; d3 += e3;
            }
            asm volatile("s_waitcnt lgkmcnt(0)" ::: "memory");  // prior chunk's reads done
            srw[lane] = src;
            float4 ev = {e0, e1, e2, e3};
            *(float4*)(exw + lane * 4) = ev;
            asm volatile("s_waitcnt lgkmcnt(0)" ::: "memory");  // writes visible wave-wide
            for (int e = 0; e < nedge; e += 16) {
                int ea = e + sub, eb = e + 4 + sub, ec = e + 8 + sub, ed = e + 12 + sub;
                int sa = srw[ea], sb = srw[eb], sc = srw[ec], sd = srw[ed];
                float xa = exw[ea * 4 + hh];
                float xb = exw[eb * 4 + hh];
                float xc = exw[ec * 4 + hh];
                float xd = exw[ed * 4 + hh];
                uint4 ua = hb4[(size_t)sa * 16 + fl];
                uint4 ub = hb4[(size_t)sb * 16 + fl];
                uint4 uc = hb4[(size_t)sc * 16 + fl];
                uint4 ud = hb4[(size_t)sd * 16 + fl];
                accA.x += xa * bf16lo(ua.x) + xb * bf16lo(ub.x) + xc * bf16lo(uc.x) + xd * bf16lo(ud.x);
                accA.y += xa * bf16hi(ua.x) + xb * bf16hi(ub.x) + xc * bf16hi(uc.x) + xd * bf16hi(ud.x);
                accA.z += xa * bf16lo(ua.y) + xb * bf16lo(ub.y) + xc * bf16lo(uc.y) + xd * bf16lo(ud.y);
                accA.w += xa * bf16hi(ua.y) + xb * bf16hi(ub.y) + xc * bf16hi(uc.y) + xd * bf16hi(ud.y);
                accB.x += xa * bf16lo(ua.z) + xb * bf16lo(ub.z) + xc * bf16lo(uc.z) + xd * bf16lo(ud.z);
                accB.y += xa * bf16hi(ua.z) + xb * bf16hi(ub.z) + xc * bf16hi(uc.z) + xd * bf16hi(ud.z);
                accB.z += xa * bf16lo(ua.w) + xb * bf16lo(ub.w) + xc * bf16lo(uc.w) + xd * bf16lo(ud.w);
                accB.w += xa * bf16hi(ua.w) + xb * bf16hi(ub.w) + xc * bf16hi(uc.w) + xd * bf16hi(ud.w);
            }
        }
    }

    // reduce denominators across lanes
#pragma unroll
    for (int off = 32; off; off >>= 1) {
        d0 += __shfl_xor(d0, off); d1 += __shfl_xor(d1, off);
        d2 += __shfl_xor(d2, off); d3 += __shfl_xor(d3, off);
    }
    // combine the 4 edge sub-slots
#pragma unroll
    for (int off = 16; off <= 32; off <<= 1) {
        accA.x += __shfl_xor(accA.x, off); accA.y += __shfl_xor(accA.y, off);
        accA.z += __shfl_xor(accA.z, off); accA.w += __shfl_xor(accA.w, off);
        accB.x += __shfl_xor(accB.x, off); accB.y += __shfl_xor(accB.y, off);
        accB.z += __shfl_xor(accB.z, off); accB.w += __shfl_xor(accB.w, off);
    }

    if (lane < 16) {
        float denh = (hh == 0) ? d0 : (hh == 1) ? d1 : (hh == 2) ? d2 : d3;
        float inv = 1.0f / (denh + EPS);
        int f0 = lane * 8;
        float4 ba = *(const float4*)(b1 + f0);
        float4 bb = *(const float4*)(b1 + f0 + 4);
        float4 oa, ob;
        oa.x = accA.x * inv + ba.x; oa.x = oa.x > 0.0f ? oa.x : 0.0f;
        oa.y = accA.y * inv + ba.y; oa.y = oa.y > 0.0f ? oa.y : 0.0f;
        oa.z = accA.z * inv + ba.z; oa.z = oa.z > 0.0f ? oa.z : 0.0f;
        oa.w = accA.w * inv + ba.w; oa.w = oa.w > 0.0f ? oa.w : 0.0f;
        ob.x = accB.x * inv + bb.x; ob.x = ob.x > 0.0f ? ob.x : 0.0f;
        ob.y = accB.y * inv + bb.y; ob.y = ob.y > 0.0f ? ob.y : 0.0f;
        ob.z = accB.z * inv + bb.z; ob.z = ob.z > 0.0f ? ob.z : 0.0f;
        ob.w = accB.w * inv + bb.w; ob.w = ob.w > 0.0f ? ob.w : 0.0f;
        *(float4*)(out1 + (size_t)dst * 128 + f0) = oa;
        *(float4*)(out1 + (size_t)dst * 128 + f0 + 4) = ob;
    }
}

// ---------------- layer 2 GEMM + alpha (LDS-staged W2, bf16 h2 out) --------
__global__ __launch_bounds__(256) void k_gemm2(const float* __restrict__ out1,
                                               const float* __restrict__ W2,
                                               const float* __restrict__ a_src,
                                               const float* __restrict__ a_dst,
                                               unsigned* __restrict__ h2bf,
                                               float* __restrict__ as2,
                                               float* __restrict__ ad2, int N) {
    __shared__ float sW[128 * 32];   // 16 KB, [k][col]
    int tid = threadIdx.x;

    {
        float4* dst = (float4*)sW;
        const float4* srcp = (const float4*)W2;
#pragma unroll
        for (int i = 0; i < 4; ++i) dst[tid + 256 * i] = srcp[tid + 256 * i];
    }
    __syncthreads();

    int c4 = tid & 7;              // col quad 0..7
    int rq = tid >> 3;             // row quad 0..31
    int r0 = blockIdx.x * 128 + rq * 4;
    if (r0 >= N) return;
    const float* xr0 = out1 + (size_t)min(r0 + 0, N - 1) * 128;
    const float* xr1 = out1 + (size_t)min(r0 + 1, N - 1) * 128;
    const float* xr2 = out1 + (size_t)min(r0 + 2, N - 1) * 128;
    const float* xr3 = out1 + (size_t)min(r0 + 3, N - 1) * 128;
    const float4* wS = (const float4*)sW;   // [128][8]

    float4 acc0 = {0,0,0,0}, acc1 = {0,0,0,0}, acc2 = {0,0,0,0}, acc3 = {0,0,0,0};
#pragma unroll 2
    for (int k4 = 0; k4 < 32; ++k4) {
        float4 xa = *(const float4*)(xr0 + k4 * 4);
        float4 xb = *(const float4*)(xr1 + k4 * 4);
        float4 xc = *(const float4*)(xr2 + k4 * 4);
        float4 xd = *(const float4*)(xr3 + k4 * 4);
        float4 w0 = wS[(k4 * 4 + 0) * 8 + c4];
        float4 w1 = wS[(k4 * 4 + 1) * 8 + c4];
        float4 w2 = wS[(k4 * 4 + 2) * 8 + c4];
        float4 w3 = wS[(k4 * 4 + 3) * 8 + c4];
        acc0.x += xa.x*w0.x + xa.y*w1.x + xa.z*w2.x + xa.w*w3.x;
        acc0.y += xa.x*w0.y + xa.y*w1.y + xa.z*w2.y + xa.w*w3.y;
        acc0.z += xa.x*w0.z + xa.y*w1.z + xa.z*w2.z + xa.w*w3.z;
        acc0.w += xa.x*w0.w + xa.y*w1.w + xa.z*w2.w + xa.w*w3.w;
        acc1.x += xb.x*w0.x + xb.y*w1.x + xb.z*w2.x + xb.w*w3.x;
        acc1.y += xb.x*w0.y + xb.y*w1.y + xb.z*w2.y + xb.w*w3.y;
        acc1.z += xb.x*w0.z + xb.y*w1.z + xb.z*w2.z + xb.w*w3.z;
        acc1.w += xb.x*w0.w + xb.y*w1.w + xb.z*w2.w + xb.w*w3.w;
        acc2.x += xc.x*w0.x + xc.y*w1.x + xc.z*w2.x + xc.w*w3.x;
        acc2.y += xc.x*w0.y + xc.y*w1.y + xc.z*w2.y + xc.w*w3.y;
        acc2.z += xc.x*w0.z + xc.y*w1.z + xc.z*w2.z + xc.w*w3.z;
        acc2.w += xc.x*w0.w + xc.y*w1.w + xc.z*w2.w + xc.w*w3.w;
        acc3.x += xd.x*w0.x + xd.y*w1.x + xd.z*w2.x + xd.w*w3.x;
        acc3.y += xd.x*w0.y + xd.y*w1.y + xd.z*w2.y + xd.w*w3.y;
        acc3.z += xd.x*w0.z + xd.y*w1.z + xd.z*w2.z + xd.w*w3.z;
        acc3.w += xd.x*w0.w + xd.y*w1.w + xd.z*w2.w + xd.w*w3.w;
    }

    uint2 q0 = { bf16pack2(acc0.x, acc0.y), bf16pack2(acc0.z, acc0.w) };
    uint2 q1 = { bf16pack2(acc1.x, acc1.y), bf16pack2(acc1.z, acc1.w) };
    uint2 q2 = { bf16pack2(acc2.x, acc2.y), bf16pack2(acc2.z, acc2.w) };
    uint2 q3 = { bf16pack2(acc3.x, acc3.y), bf16pack2(acc3.z, acc3.w) };
    uint2* hb = (uint2*)h2bf;
    if (r0 + 0 < N) hb[(size_t)(r0 + 0) * 8 + c4] = q0;
    if (r0 + 1 < N) hb[(size_t)(r0 + 1) * 8 + c4] = q1;
    if (r0 + 2 < N) hb[(size_t)(r0 + 2) * 8 + c4] = q2;
    if (r0 + 3 < N) hb[(size_t)(r0 + 3) * 8 + c4] = q3;

    float4 av = ((const float4*)a_src)[c4];
    float4 dv = ((const float4*)a_dst)[c4];
    float s0 = acc0.x*av.x + acc0.y*av.y + acc0.z*av.z + acc0.w*av.w;
    float s1 = acc1.x*av.x + acc1.y*av.y + acc1.z*av.z + acc1.w*av.w;
    float s2 = acc2.x*av.x + acc2.y*av.y + acc2.z*av.z + acc2.w*av.w;
    float s3 = acc3.x*av.x + acc3.y*av.y + acc3.z*av.z + acc3.w*av.w;
    float d0 = acc0.x*dv.x + acc0.y*dv.y + acc0.z*dv.z + acc0.w*dv.w;
    float d1 = acc1.x*dv.x + acc1.y*dv.y + acc1.z*dv.z + acc1.w*dv.w;
    float d2 = acc2.x*dv.x + acc2.y*dv.y + acc2.z*dv.z + acc2.w*dv.w;
    float d3 = acc3.x*dv.x + acc3.y*dv.y + acc3.z*dv.z + acc3.w*dv.w;
#pragma unroll
    for (int off = 1; off < 8; off <<= 1) {
        s0 += __shfl_xor(s0, off); s1 += __shfl_xor(s1, off);
        s2 += __shfl_xor(s2, off); s3 += __shfl_xor(s3, off);
        d0 += __shfl_xor(d0, off); d1 += __shfl_xor(d1, off);
        d2 += __shfl_xor(d2, off); d3 += __shfl_xor(d3, off);
    }
    if (c4 == 0) {
        if (r0 + 0 < N) { as2[r0 + 0] = s0; ad2[r0 + 0] = d0; }
        if (r0 + 1 < N) { as2[r0 + 1] = s1; ad2[r0 + 1] = d1; }
        if (r0 + 2 < N) { as2[r0 + 2] = s2; ad2[r0 + 2] = d2; }
        if (r0 + 3 < N) { as2[r0 + 3] = s3; ad2[r0 + 3] = d3; }
    }
}

// ---------------- layer 2 fused gather + final linear (ONLINE, 8/iter) -----
__global__ __launch_bounds__(256) void k_gather2(const int* __restrict__ rowptr,
                                                 const int* __restrict__ col,
                                                 const float* __restrict__ as2,
                                                 const float* __restrict__ ad2,
                                                 const unsigned short* __restrict__ h2b,
                                                 const float* __restrict__ b2,
                                                 const float* __restrict__ W_lin,
                                                 const float* __restrict__ b_lin,
                                                 float* __restrict__ out, int N) {
    int tid = threadIdx.x;
    int swid = (blockIdx.x * blockDim.x + tid) >> 5;
    if (swid >= N) return;
    int c = tid & 31;
    int dst = swid;
    int start = rowptr[dst], end = rowptr[dst + 1];
    float adv = ad2[dst];

    float m = -INFINITY, acc = 0.0f, den = 0.0f;
    int j = start;
    for (; j + 7 < end; j += 8) {
        int s0 = col[j],     s1 = col[j + 1], s2 = col[j + 2], s3 = col[j + 3];
        int s4 = col[j + 4], s5 = col[j + 5], s6 = col[j + 6], s7 = col[j + 7];
        float l0 = leaky(as2[s0] + adv), l1 = leaky(as2[s1] + adv);
        float l2 = leaky(as2[s2] + adv), l3 = leaky(as2[s3] + adv);
        float l4 = leaky(as2[s4] + adv), l5 = leaky(as2[s5] + adv);
        float l6 = leaky(as2[s6] + adv), l7 = leaky(as2[s7] + adv);
        unsigned short u0 = h2b[(size_t)s0 * 32 + c];
        unsigned short u1 = h2b[(size_t)s1 * 32 + c];
        unsigned short u2 = h2b[(size_t)s2 * 32 + c];
        unsigned short u3 = h2b[(size_t)s3 * 32 + c];
        unsigned short u4 = h2b[(size_t)s4 * 32 + c];
        unsigned short u5 = h2b[(size_t)s5 * 32 + c];
        unsigned short u6 = h2b[(size_t)s6 * 32 + c];
        unsigned short u7 = h2b[(size_t)s7 * 32 + c];
        float ma = fmaxf(fmaxf(l0, l1), fmaxf(l2, l3));
        float mb = fmaxf(fmaxf(l4, l5), fmaxf(l6, l7));
        float m8 = fmaxf(ma, mb);
        if (m8 > m) {                       // uniform within half-wave
            float sc = __expf(m - m8);
            acc *= sc; den *= sc; m = m8;
        }
        float x0 = __expf(l0 - m), x1 = __expf(l1 - m);
        float x2 = __expf(l2 - m), x3 = __expf(l3 - m);
        float x4 = __expf(l4 - m), x5 = __expf(l5 - m);
        float x6 = __expf(l6 - m), x7 = __expf(l7 - m);
        den += ((x0 + x1) + (x2 + x3)) + ((x4 + x5) + (x6 + x7));
        acc += x0 * __uint_as_float(((unsigned)u0) << 16)
             + x1 * __uint_as_float(((unsigned)u1) << 16)
             + x2 * __uint_as_float(((unsigned)u2) << 16)
             + x3 * __uint_as_float(((unsigned)u3) << 16)
             + x4 * __uint_as_float(((unsigned)u4) << 16)
             + x5 * __uint_as_float(((unsigned)u5) << 16)
             + x6 * __uint_as_float(((unsigned)u6) << 16)
             + x7 * __uint_as_float(((unsigned)u7) << 16);
    }
    for (; j < end; ++j) {
        int src = col[j];
        float l = leaky(as2[src] + adv);
        unsigned short u = h2b[(size_t)src * 32 + c];
        if (l > m) {
            float sc = __expf(m - l);
            acc *= sc; den *= sc; m = l;
        }
        float ex = __expf(l - m);
        den += ex;
        acc += ex * __uint_as_float(((unsigned)u) << 16);
    }

    float v = acc / (den + EPS) + b2[c];
    v = v > 0.0f ? v : 0.0f;

    // final linear: dot(v, W_lin) + b_lin
    float w = v * W_lin[c];
#pragma unroll
    for (int off = 16; off; off >>= 1) w += __shfl_xor(w, off, 32);
    if (c == 0) out[dst] = w + b_lin[0];
}

extern "C" void kernel_launch(void* const* d_in, const int* in_sizes, int n_in,
                              void* d_out, int out_size, void* d_ws, size_t ws_size,
                              hipStream_t stream) {
    const float* x      = (const float*)d_in[0];
    const int*   ei     = (const int*)d_in[1];
    // d_in[2] = batch (unused)
    const float* W1     = (const float*)d_in[3];
    const float* a_src1 = (const float*)d_in[4];
    const float* a_dst1 = (const float*)d_in[5];
    const float* b1     = (const float*)d_in[6];
    const float* W2     = (const float*)d_in[7];
    const float* a_src2 = (const float*)d_in[8];
    const float* a_dst2 = (const float*)d_in[9];
    const float* b2     = (const float*)d_in[10];
    const float* W_lin  = (const float*)d_in[11];
    const float* b_lin  = (const float*)d_in[12];
    float* out = (float*)d_out;

    const int N = in_sizes[0] / 64;
    const int E = in_sizes[1] / 2;
    const int T = E + N;               // total edges incl. self-loops
    const int NB = (N + 255) >> 8;     // buckets of 256 dst nodes (<=512)

    // workspace layout
    float* ws = (float*)d_ws;
    size_t off = 0;
    float* h1reg = ws + off; off += (size_t)N * 128;  // h1bf uses N*64 uints; spare upper half hosts binned
    float* out1 = ws + off; off += (size_t)N * 128;
    float* as1  = ws + off; off += (size_t)N * 4;
    float* ad1  = ws + off; off += (size_t)N * 4;
    float* as2  = ws + off; off += (size_t)N;
    float* ad2  = ws + off; off += (size_t)N;
    int* rowptr    = (int*)(ws + off); off += (size_t)N + 4;
    int* bucketptr = (int*)(ws + off); off += 1024;   // NB+1 <= 513
    int* bhist     = (int*)(ws + off); off += 512;
    int* bcursor   = (int*)(ws + off); off += 512;
    int* colarr    = (int*)(ws + off); off += (size_t)T;
    unsigned* h1bf = (unsigned*)h1reg;                       // N*64 uints (bf16x2)
    unsigned* h2bf = (unsigned*)h1reg;                       // reuses h1reg after gather1
    unsigned* binned = (unsigned*)h1reg + (size_t)N * 64;    // T uints in h1reg's spare half

    const int B = 256;
    auto blocks = [](size_t t, int b) { return (unsigned)((t + b - 1) / b); };

    // bucket-binned CSR build
    hipMemsetAsync(bhist, 0, 512 * sizeof(int), stream);
    k_binhist<<<256, 256, 0, stream>>>(ei, bhist, E, N);
    k_binscan<<<1, 512, 0, stream>>>(bhist, bucketptr, bcursor, rowptr, NB, N, T);
    k_binfill<<<blocks(T, BF_CHUNK), 512, 0, stream>>>(ei, bcursor, binned, E, N);

    // fat kernel: bucketfill (CSR tail) + gemm1 (independent) overlapped
    k_bucketfill_gemm1<<<(unsigned)(NB + (N + 31) / 32), B, 0, stream>>>(
        binned, bucketptr, rowptr, colarr,
        x, W1, a_src1, a_dst1, h1bf, as1, ad1, N, NB);

    // layer 1 gather (single-chunk fast path, 16 edges/iter)
    k_gather1<<<(unsigned)((N + 3) / 4), B, 0, stream>>>(rowptr, colarr, as1, ad1, h1bf, b1, out1, N);

    // layer 2 (+ fused final linear)
    k_gemm2  <<<(unsigned)((N + 127) / 128), B, 0, stream>>>(out1, W2, a_src2, a_dst2, h2bf, as2, ad2, N);
    k_gather2<<<blocks((size_t)N * 32, B), B, 0, stream>>>(rowptr, colarr, as2, ad2,
                                                           (const unsigned short*)h2bf, b2, W_lin, b_lin, out, N);
}

// Round 8
// 319.568 us; speedup vs baseline: 1.0196x; 1.0196x over previous
//
#include <hip/hip_runtime.h>
#include <math.h>

#define NEG_SLOPE 0.2f
#define EPS 1e-16f

__device__ inline float leaky(float v) {
    return v >= 0.0f ? v : NEG_SLOPE * v;
}

// pack two floats into bf16x2 (RNE), low half = first arg
__device__ inline unsigned bf16pack2(float a, float b) {
    unsigned ua = __float_as_uint(a);
    unsigned ub = __float_as_uint(b);
    ua = (ua + 0x7FFFu + ((ua >> 16) & 1u)) >> 16;
    ub = (ub + 0x7FFFu + ((ub >> 16) & 1u)) >> 16;
    return ua | (ub << 16);
}

__device__ inline float bf16lo(unsigned u) { return __uint_as_float(u << 16); }
__device__ inline float bf16hi(unsigned u) { return __uint_as_float(u & 0xFFFF0000u); }

// ================= bucket-binned CSR build =================
// Buckets of 256 dst nodes. Packed binned entry: (src << 8) | (dst & 255).
// Requires src < 2^24 and nbuckets <= 512 (N <= 131072).

// per-block LDS-aggregated bucket histogram over all T = E+N entries
__global__ __launch_bounds__(256) void k_binhist(const int* __restrict__ ei, int* __restrict__ bhist,
                                                 int E, int N) {
    __shared__ int sh[512];
    int tid = threadIdx.x;
    sh[tid] = 0; sh[tid + 256] = 0;
    __syncthreads();
    int T = E + N;
    int stride = gridDim.x * 256;
    for (int t = blockIdx.x * 256 + tid; t < T; t += stride) {
        int d = (t < E) ? ei[E + t] : (t - E);
        atomicAdd(&sh[d >> 8], 1);
    }
    __syncthreads();
    int c0 = sh[tid];       if (c0) atomicAdd(&bhist[tid], c0);
    int c1 = sh[tid + 256]; if (c1) atomicAdd(&bhist[tid + 256], c1);
}

// one-block exclusive scan of bucket counts -> bucketptr, bcursor; rowptr[N]=T
__global__ __launch_bounds__(512) void k_binscan(const int* __restrict__ bhist,
                                                 int* __restrict__ bucketptr,
                                                 int* __restrict__ bcursor,
                                                 int* __restrict__ rowptr,
                                                 int nb, int N, int T) {
    __shared__ int s[512];
    int tid = threadIdx.x;
    int v = (tid < nb) ? bhist[tid] : 0;
    s[tid] = v;
    __syncthreads();
#pragma unroll
    for (int off = 1; off < 512; off <<= 1) {
        int t = (tid >= off) ? s[tid - off] : 0;
        __syncthreads();
        s[tid] += t;
        __syncthreads();
    }
    int excl = s[tid] - v;
    if (tid < nb) { bucketptr[tid] = excl; bcursor[tid] = excl; }
    else          { bcursor[tid] = 0; }
    if (tid == 0) { bucketptr[nb] = T; rowptr[N] = T; }
}

// bin edges into bucket-contiguous regions (one atomic reservation per
// bucket per block; packed writes into reserved runs -> L2-coalesced).
#define BF_CHUNK 8192
__global__ __launch_bounds__(512) void k_binfill(const int* __restrict__ ei,
                                                 int* __restrict__ bcursor,
                                                 unsigned* __restrict__ binned,
                                                 int E, int N) {
    __shared__ int h[512], lc[512], gb[512];
    int tid = threadIdx.x;
    int T = E + N;
    int base = blockIdx.x * BF_CHUNK;
    int n = T - base; if (n > BF_CHUNK) n = BF_CHUNK;
    h[tid] = 0; lc[tid] = 0;
    __syncthreads();
    for (int i = tid; i < n; i += 512) {
        int t = base + i;
        int d = (t < E) ? ei[E + t] : (t - E);
        atomicAdd(&h[d >> 8], 1);
    }
    __syncthreads();
    if (h[tid] > 0) gb[tid] = atomicAdd(&bcursor[tid], h[tid]);
    __syncthreads();
    for (int i = tid; i < n; i += 512) {
        int t = base + i;
        int s, d;
        if (t < E) { s = ei[t]; d = ei[E + t]; } else { s = d = t - E; }
        int b = d >> 8;
        int slot = atomicAdd(&lc[b], 1);
        binned[gb[b] + slot] = ((unsigned)s << 8) | (unsigned)(d & 255);
    }
}

// ---------------- fat kernel: bucketfill (blocks < NB) + gemm1 (rest) ------
__global__ __launch_bounds__(256) void k_bucketfill_gemm1(
        const unsigned* __restrict__ binned, const int* __restrict__ bucketptr,
        int* __restrict__ rowptr, int* __restrict__ col,
        const float* __restrict__ x, const float* __restrict__ W1,
        const float* __restrict__ a_src, const float* __restrict__ a_dst,
        unsigned* __restrict__ h1bf, float* __restrict__ as1,
        float* __restrict__ ad1, int N, int nbuckets) {
    __shared__ float smem[64 * 128 + 32 * 64];   // 40 KB, aliased by role
    int tid = threadIdx.x;

    if ((int)blockIdx.x < nbuckets) {
        // ---- bucketfill role (256 threads) ----
        int* h  = (int*)smem;
        int* o  = h + 256;
        int* lc = o + 256;
        int b = blockIdx.x;
        int gs = bucketptr[b], ge = bucketptr[b + 1];
        h[tid] = 0; lc[tid] = 0;
        __syncthreads();
        for (int j = gs + tid; j < ge; j += 256)
            atomicAdd(&h[binned[j] & 255], 1);
        __syncthreads();
        int v = h[tid];
        o[tid] = v;
        __syncthreads();
#pragma unroll
        for (int off = 1; off < 256; off <<= 1) {
            int t = (tid >= off) ? o[tid - off] : 0;
            __syncthreads();
            o[tid] += t;
            __syncthreads();
        }
        int excl = o[tid] - v;
        int dst0 = b << 8;
        if (dst0 + tid < N) rowptr[dst0 + tid] = gs + excl;
        o[tid] = excl;
        __syncthreads();
        for (int j = gs + tid; j < ge; j += 256) {
            unsigned pv = binned[j];
            int d = pv & 255;
            int s = (int)(pv >> 8);
            int slot = atomicAdd(&lc[d], 1);
            col[gs + o[d] + slot] = s;
        }
        return;
    }

    // ---- gemm1 role ----
    float* sW = smem;                 // [64][128]
    float* sX = smem + 64 * 128;      // [32][64]
    int block_r0 = ((int)blockIdx.x - nbuckets) * 32;

    {
        float4* dst = (float4*)sW;
        const float4* srcp = (const float4*)W1;
#pragma unroll
        for (int i = 0; i < 8; ++i) dst[tid + 256 * i] = srcp[tid + 256 * i];
    }
    {
        float4* dst = (float4*)sX;
#pragma unroll
        for (int i = 0; i < 2; ++i) {
            int idx = tid + 256 * i;
            int r = idx >> 4;            // 0..31
            int c = idx & 15;            // float4 within row
            int gr = min(block_r0 + r, N - 1);
            dst[idx] = ((const float4*)(x + (size_t)gr * 64))[c];
        }
    }
    __syncthreads();

    int c4 = tid & 31;             // col quad 0..31
    int rq = tid >> 5;             // row quad 0..7
    int r0 = block_r0 + rq * 4;
    const float4* wS = (const float4*)sW;   // [64][32]
    const float4* xS = (const float4*)sX;   // [32][16]

    float4 acc0 = {0,0,0,0}, acc1 = {0,0,0,0}, acc2 = {0,0,0,0}, acc3 = {0,0,0,0};
#pragma unroll 2
    for (int k4 = 0; k4 < 16; ++k4) {
        float4 xa = xS[(rq * 4 + 0) * 16 + k4];
        float4 xb = xS[(rq * 4 + 1) * 16 + k4];
        float4 xc = xS[(rq * 4 + 2) * 16 + k4];
        float4 xd = xS[(rq * 4 + 3) * 16 + k4];
        float4 w0 = wS[(k4 * 4 + 0) * 32 + c4];
        float4 w1 = wS[(k4 * 4 + 1) * 32 + c4];
        float4 w2 = wS[(k4 * 4 + 2) * 32 + c4];
        float4 w3 = wS[(k4 * 4 + 3) * 32 + c4];
        acc0.x += xa.x*w0.x + xa.y*w1.x + xa.z*w2.x + xa.w*w3.x;
        acc0.y += xa.x*w0.y + xa.y*w1.y + xa.z*w2.y + xa.w*w3.y;
        acc0.z += xa.x*w0.z + xa.y*w1.z + xa.z*w2.z + xa.w*w3.z;
        acc0.w += xa.x*w0.w + xa.y*w1.w + xa.z*w2.w + xa.w*w3.w;
        acc1.x += xb.x*w0.x + xb.y*w1.x + xb.z*w2.x + xb.w*w3.x;
        acc1.y += xb.x*w0.y + xb.y*w1.y + xb.z*w2.y + xb.w*w3.y;
        acc1.z += xb.x*w0.z + xb.y*w1.z + xb.z*w2.z + xb.w*w3.z;
        acc1.w += xb.x*w0.w + xb.y*w1.w + xb.z*w2.w + xb.w*w3.w;
        acc2.x += xc.x*w0.x + xc.y*w1.x + xc.z*w2.x + xc.w*w3.x;
        acc2.y += xc.x*w0.y + xc.y*w1.y + xc.z*w2.y + xc.w*w3.y;
        acc2.z += xc.x*w0.z + xc.y*w1.z + xc.z*w2.z + xc.w*w3.z;
        acc2.w += xc.x*w0.w + xc.y*w1.w + xc.z*w2.w + xc.w*w3.w;
        acc3.x += xd.x*w0.x + xd.y*w1.x + xd.z*w2.x + xd.w*w3.x;
        acc3.y += xd.x*w0.y + xd.y*w1.y + xd.z*w2.y + xd.w*w3.y;
        acc3.z += xd.x*w0.z + xd.y*w1.z + xd.z*w2.z + xd.w*w3.z;
        acc3.w += xd.x*w0.w + xd.y*w1.w + xd.z*w2.w + xd.w*w3.w;
    }

    uint2 p0 = { bf16pack2(acc0.x, acc0.y), bf16pack2(acc0.z, acc0.w) };
    uint2 p1 = { bf16pack2(acc1.x, acc1.y), bf16pack2(acc1.z, acc1.w) };
    uint2 p2 = { bf16pack2(acc2.x, acc2.y), bf16pack2(acc2.z, acc2.w) };
    uint2 p3 = { bf16pack2(acc3.x, acc3.y), bf16pack2(acc3.z, acc3.w) };
    uint2* hb = (uint2*)h1bf;
    if (r0 + 0 < N) hb[(size_t)(r0 + 0) * 32 + c4] = p0;
    if (r0 + 1 < N) hb[(size_t)(r0 + 1) * 32 + c4] = p1;
    if (r0 + 2 < N) hb[(size_t)(r0 + 2) * 32 + c4] = p2;
    if (r0 + 3 < N) hb[(size_t)(r0 + 3) * 32 + c4] = p3;

    float4 av = ((const float4*)a_src)[c4];
    float4 dv = ((const float4*)a_dst)[c4];
    float s0 = acc0.x*av.x + acc0.y*av.y + acc0.z*av.z + acc0.w*av.w;
    float s1 = acc1.x*av.x + acc1.y*av.y + acc1.z*av.z + acc1.w*av.w;
    float s2 = acc2.x*av.x + acc2.y*av.y + acc2.z*av.z + acc2.w*av.w;
    float s3 = acc3.x*av.x + acc3.y*av.y + acc3.z*av.z + acc3.w*av.w;
    float d0 = acc0.x*dv.x + acc0.y*dv.y + acc0.z*dv.z + acc0.w*dv.w;
    float d1 = acc1.x*dv.x + acc1.y*dv.y + acc1.z*dv.z + acc1.w*dv.w;
    float d2 = acc2.x*dv.x + acc2.y*dv.y + acc2.z*dv.z + acc2.w*dv.w;
    float d3 = acc3.x*dv.x + acc3.y*dv.y + acc3.z*dv.z + acc3.w*dv.w;
#pragma unroll
    for (int off = 1; off < 8; off <<= 1) {
        s0 += __shfl_xor(s0, off); s1 += __shfl_xor(s1, off);
        s2 += __shfl_xor(s2, off); s3 += __shfl_xor(s3, off);
        d0 += __shfl_xor(d0, off); d1 += __shfl_xor(d1, off);
        d2 += __shfl_xor(d2, off); d3 += __shfl_xor(d3, off);
    }
    if ((c4 & 7) == 0) {
        int h = c4 >> 3;
        if (r0 + 0 < N) { as1[(r0 + 0) * 4 + h] = s0; ad1[(r0 + 0) * 4 + h] = d0; }
        if (r0 + 1 < N) { as1[(r0 + 1) * 4 + h] = s1; ad1[(r0 + 1) * 4 + h] = d1; }
        if (r0 + 2 < N) { as1[(r0 + 2) * 4 + h] = s2; ad1[(r0 + 2) * 4 + h] = d2; }
        if (r0 + 3 < N) { as1[(r0 + 3) * 4 + h] = s3; ad1[(r0 + 3) * 4 + h] = d3; }
    }
}

// ---------------- layer 1 fused gather: two-pass softmax, 8 edges/iter -----
// (R6 best-measured form: MLP-2, VGPR 32, occupancy ~76%)
__global__ __launch_bounds__(256) void k_gather1(const int* __restrict__ rowptr,
                                                 const int* __restrict__ col,
                                                 const float* __restrict__ as1,
                                                 const float* __restrict__ ad1,
                                                 const unsigned* __restrict__ h1bf,
                                                 const float* __restrict__ b1,
                                                 float* __restrict__ out1, int N) {
    __shared__ float s_ex[4][64 * 4];   // [wave][edge*4+head]
    __shared__ int   s_src[4][64];      // [wave][edge]
    int tid = threadIdx.x;
    int wv = tid >> 6;
    int lane = tid & 63;
    int dst = blockIdx.x * 4 + wv;
    if (dst >= N) return;
    int start = rowptr[dst], end = rowptr[dst + 1];
    float4 ad = *(const float4*)(ad1 + (size_t)dst * 4);

    // phase A: per-head max (lane-per-edge, strided)
    float m0 = -INFINITY, m1 = -INFINITY, m2 = -INFINITY, m3 = -INFINITY;
    for (int j = start + lane; j < end; j += 64) {
        int src = col[j];
        float4 a = *(const float4*)(as1 + (size_t)src * 4);
        m0 = fmaxf(m0, leaky(a.x + ad.x));
        m1 = fmaxf(m1, leaky(a.y + ad.y));
        m2 = fmaxf(m2, leaky(a.z + ad.z));
        m3 = fmaxf(m3, leaky(a.w + ad.w));
    }
#pragma unroll
    for (int off = 32; off; off >>= 1) {
        m0 = fmaxf(m0, __shfl_xor(m0, off));
        m1 = fmaxf(m1, __shfl_xor(m1, off));
        m2 = fmaxf(m2, __shfl_xor(m2, off));
        m3 = fmaxf(m3, __shfl_xor(m3, off));
    }

    int sub = lane >> 4;           // edge slot 0..3
    int fl = lane & 15;            // uint4 index (features fl*8 .. fl*8+7)
    int hh = fl >> 2;              // head of this lane's features
    const uint4* hb4 = (const uint4*)h1bf;
    float* exw = s_ex[wv];
    int* srw = s_src[wv];

    float d0 = 0, d1 = 0, d2 = 0, d3 = 0;            // softmax denominators
    float4 accA = {0,0,0,0}, accB = {0,0,0,0};       // 8 features per lane

    for (int base = start; base < end; base += 64) {
        int nedge = end - base; if (nedge > 64) nedge = 64;
        // phase B: lane-per-edge exp (inactive lanes pad with ex=0, src=0)
        float e0 = 0, e1 = 0, e2 = 0, e3 = 0;
        int src = 0;
        if (lane < nedge) {
            src = col[base + lane];
            float4 a = *(const float4*)(as1 + (size_t)src * 4);
            e0 = __expf(leaky(a.x + ad.x) - m0);
            e1 = __expf(leaky(a.y + ad.y) - m1);
            e2 = __expf(leaky(a.z + ad.z) - m2);
            e3 = __expf(leaky(a.w + ad.w) - m3);
            d0 += e0; d1 += e1; d2 += e2; d3 += e3;
        }
        asm volatile("s_waitcnt lgkmcnt(0)" ::: "memory");  // prior chunk's reads done
        srw[lane] = src;
        float4 ev = {e0, e1, e2, e3};
        *(float4*)(exw + lane * 4) = ev;
        asm volatile("s_waitcnt lgkmcnt(0)" ::: "memory");  // writes visible wave-wide
        // phase C: 8 edges per iteration, two independent gathers per lane
        for (int e = 0; e < nedge; e += 8) {
            int ea = e + sub;                 // <= 59
            int eb = e + 4 + sub;             // <= 63
            int sa = srw[ea];
            int sb = srw[eb];
            float xa = exw[ea * 4 + hh];
            float xb = exw[eb * 4 + hh];
            uint4 ua = hb4[(size_t)sa * 16 + fl];
            uint4 ub = hb4[(size_t)sb * 16 + fl];
            accA.x += xa * bf16lo(ua.x) + xb * bf16lo(ub.x);
            accA.y += xa * bf16hi(ua.x) + xb * bf16hi(ub.x);
            accA.z += xa * bf16lo(ua.y) + xb * bf16lo(ub.y);
            accA.w += xa * bf16hi(ua.y) + xb * bf16hi(ub.y);
            accB.x += xa * bf16lo(ua.z) + xb * bf16lo(ub.z);
            accB.y += xa * bf16hi(ua.z) + xb * bf16hi(ub.z);
            accB.z += xa * bf16lo(ua.w) + xb * bf16lo(ub.w);
            accB.w += xa * bf16hi(ua.w) + xb * bf16hi(ub.w);
        }
    }

    // reduce denominators across lanes
#pragma unroll
    for (int off = 32; off; off >>= 1) {
        d0 += __shfl_xor(d0, off); d1 += __shfl_xor(d1, off);
        d2 += __shfl_xor(d2, off); d3 += __shfl_xor(d3, off);
    }
    // combine the 4 edge sub-slots
#pragma unroll
    for (int off = 16; off <= 32; off <<= 1) {
        accA.x += __shfl_xor(accA.x, off); accA.y += __shfl_xor(accA.y, off);
        accA.z += __shfl_xor(accA.z, off); accA.w += __shfl_xor(accA.w, off);
        accB.x += __shfl_xor(accB.x, off); accB.y += __shfl_xor(accB.y, off);
        accB.z += __shfl_xor(accB.z, off); accB.w += __shfl_xor(accB.w, off);
    }

    if (lane < 16) {
        float denh = (hh == 0) ? d0 : (hh == 1) ? d1 : (hh == 2) ? d2 : d3;
        float inv = 1.0f / (denh + EPS);
        int f0 = lane * 8;
        float4 ba = *(const float4*)(b1 + f0);
        float4 bb = *(const float4*)(b1 + f0 + 4);
        float4 oa, ob;
        oa.x = accA.x * inv + ba.x; oa.x = oa.x > 0.0f ? oa.x : 0.0f;
        oa.y = accA.y * inv + ba.y; oa.y = oa.y > 0.0f ? oa.y : 0.0f;
        oa.z = accA.z * inv + ba.z; oa.z = oa.z > 0.0f ? oa.z : 0.0f;
        oa.w = accA.w * inv + ba.w; oa.w = oa.w > 0.0f ? oa.w : 0.0f;
        ob.x = accB.x * inv + bb.x; ob.x = ob.x > 0.0f ? ob.x : 0.0f;
        ob.y = accB.y * inv + bb.y; ob.y = ob.y > 0.0f ? ob.y : 0.0f;
        ob.z = accB.z * inv + bb.z; ob.z = ob.z > 0.0f ? ob.z : 0.0f;
        ob.w = accB.w * inv + bb.w; ob.w = ob.w > 0.0f ? ob.w : 0.0f;
        *(float4*)(out1 + (size_t)dst * 128 + f0) = oa;
        *(float4*)(out1 + (size_t)dst * 128 + f0 + 4) = ob;
    }
}

// ---------------- layer 2 GEMM + alpha (LDS-staged W2, bf16 h2 out) --------
__global__ __launch_bounds__(256) void k_gemm2(const float* __restrict__ out1,
                                               const float* __restrict__ W2,
                                               const float* __restrict__ a_src,
                                               const float* __restrict__ a_dst,
                                               unsigned* __restrict__ h2bf,
                                               float* __restrict__ as2,
                                               float* __restrict__ ad2, int N) {
    __shared__ float sW[128 * 32];   // 16 KB, [k][col]
    int tid = threadIdx.x;

    {
        float4* dst = (float4*)sW;
        const float4* srcp = (const float4*)W2;
#pragma unroll
        for (int i = 0; i < 4; ++i) dst[tid + 256 * i] = srcp[tid + 256 * i];
    }
    __syncthreads();

    int c4 = tid & 7;              // col quad 0..7
    int rq = tid >> 3;             // row quad 0..31
    int r0 = blockIdx.x * 128 + rq * 4;
    if (r0 >= N) return;
    const float* xr0 = out1 + (size_t)min(r0 + 0, N - 1) * 128;
    const float* xr1 = out1 + (size_t)min(r0 + 1, N - 1) * 128;
    const float* xr2 = out1 + (size_t)min(r0 + 2, N - 1) * 128;
    const float* xr3 = out1 + (size_t)min(r0 + 3, N - 1) * 128;
    const float4* wS = (const float4*)sW;   // [128][8]

    float4 acc0 = {0,0,0,0}, acc1 = {0,0,0,0}, acc2 = {0,0,0,0}, acc3 = {0,0,0,0};
#pragma unroll 2
    for (int k4 = 0; k4 < 32; ++k4) {
        float4 xa = *(const float4*)(xr0 + k4 * 4);
        float4 xb = *(const float4*)(xr1 + k4 * 4);
        float4 xc = *(const float4*)(xr2 + k4 * 4);
        float4 xd = *(const float4*)(xr3 + k4 * 4);
        float4 w0 = wS[(k4 * 4 + 0) * 8 + c4];
        float4 w1 = wS[(k4 * 4 + 1) * 8 + c4];
        float4 w2 = wS[(k4 * 4 + 2) * 8 + c4];
        float4 w3 = wS[(k4 * 4 + 3) * 8 + c4];
        acc0.x += xa.x*w0.x + xa.y*w1.x + xa.z*w2.x + xa.w*w3.x;
        acc0.y += xa.x*w0.y + xa.y*w1.y + xa.z*w2.y + xa.w*w3.y;
        acc0.z += xa.x*w0.z + xa.y*w1.z + xa.z*w2.z + xa.w*w3.z;
        acc0.w += xa.x*w0.w + xa.y*w1.w + xa.z*w2.w + xa.w*w3.w;
        acc1.x += xb.x*w0.x + xb.y*w1.x + xb.z*w2.x + xb.w*w3.x;
        acc1.y += xb.x*w0.y + xb.y*w1.y + xb.z*w2.y + xb.w*w3.y;
        acc1.z += xb.x*w0.z + xb.y*w1.z + xb.z*w2.z + xb.w*w3.z;
        acc1.w += xb.x*w0.w + xb.y*w1.w + xb.z*w2.w + xb.w*w3.w;
        acc2.x += xc.x*w0.x + xc.y*w1.x + xc.z*w2.x + xc.w*w3.x;
        acc2.y += xc.x*w0.y + xc.y*w1.y + xc.z*w2.y + xc.w*w3.y;
        acc2.z += xc.x*w0.z + xc.y*w1.z + xc.z*w2.z + xc.w*w3.z;
        acc2.w += xc.x*w0.w + xc.y*w1.w + xc.z*w2.w + xc.w*w3.w;
        acc3.x += xd.x*w0.x + xd.y*w1.x + xd.z*w2.x + xd.w*w3.x;
        acc3.y += xd.x*w0.y + xd.y*w1.y + xd.z*w2.y + xd.w*w3.y;
        acc3.z += xd.x*w0.z + xd.y*w1.z + xd.z*w2.z + xd.w*w3.z;
        acc3.w += xd.x*w0.w + xd.y*w1.w + xd.z*w2.w + xd.w*w3.w;
    }

    uint2 q0 = { bf16pack2(acc0.x, acc0.y), bf16pack2(acc0.z, acc0.w) };
    uint2 q1 = { bf16pack2(acc1.x, acc1.y), bf16pack2(acc1.z, acc1.w) };
    uint2 q2 = { bf16pack2(acc2.x, acc2.y), bf16pack2(acc2.z, acc2.w) };
    uint2 q3 = { bf16pack2(acc3.x, acc3.y), bf16pack2(acc3.z, acc3.w) };
    uint2* hb = (uint2*)h2bf;
    if (r0 + 0 < N) hb[(size_t)(r0 + 0) * 8 + c4] = q0;
    if (r0 + 1 < N) hb[(size_t)(r0 + 1) * 8 + c4] = q1;
    if (r0 + 2 < N) hb[(size_t)(r0 + 2) * 8 + c4] = q2;
    if (r0 + 3 < N) hb[(size_t)(r0 + 3) * 8 + c4] = q3;

    float4 av = ((const float4*)a_src)[c4];
    float4 dv = ((const float4*)a_dst)[c4];
    float s0 = acc0.x*av.x + acc0.y*av.y + acc0.z*av.z + acc0.w*av.w;
    float s1 = acc1.x*av.x + acc1.y*av.y + acc1.z*av.z + acc1.w*av.w;
    float s2 = acc2.x*av.x + acc2.y*av.y + acc2.z*av.z + acc2.w*av.w;
    float s3 = acc3.x*av.x + acc3.y*av.y + acc3.z*av.z + acc3.w*av.w;
    float d0 = acc0.x*dv.x + acc0.y*dv.y + acc0.z*dv.z + acc0.w*dv.w;
    float d1 = acc1.x*dv.x + acc1.y*dv.y + acc1.z*dv.z + acc1.w*dv.w;
    float d2 = acc2.x*dv.x + acc2.y*dv.y + acc2.z*dv.z + acc2.w*dv.w;
    float d3 = acc3.x*dv.x + acc3.y*dv.y + acc3.z*dv.z + acc3.w*dv.w;
#pragma unroll
    for (int off = 1; off < 8; off <<= 1) {
        s0 += __shfl_xor(s0, off); s1 += __shfl_xor(s1, off);
        s2 += __shfl_xor(s2, off); s3 += __shfl_xor(s3, off);
        d0 += __shfl_xor(d0, off); d1 += __shfl_xor(d1, off);
        d2 += __shfl_xor(d2, off); d3 += __shfl_xor(d3, off);
    }
    if (c4 == 0) {
        if (r0 + 0 < N) { as2[r0 + 0] = s0; ad2[r0 + 0] = d0; }
        if (r0 + 1 < N) { as2[r0 + 1] = s1; ad2[r0 + 1] = d1; }
        if (r0 + 2 < N) { as2[r0 + 2] = s2; ad2[r0 + 2] = d2; }
        if (r0 + 3 < N) { as2[r0 + 3] = s3; ad2[r0 + 3] = d3; }
    }
}

// ---------------- layer 2 fused gather + final linear ----------------------
// Half-wave per dst split into TWO 16-lane groups; group g owns edges
// {cb+4g .. cb+4g+3} of each 8-edge chunk with its own online-softmax state.
// Each lane loads uint (2 features) -> half the loads/exp per lane vs u16.
// Group states merged at the end via one online-softmax merge (shfl_xor 16).
__global__ __launch_bounds__(256) void k_gather2(const int* __restrict__ rowptr,
                                                 const int* __restrict__ col,
                                                 const float* __restrict__ as2,
                                                 const float* __restrict__ ad2,
                                                 const unsigned* __restrict__ h2b,
                                                 const float* __restrict__ b2,
                                                 const float* __restrict__ W_lin,
                                                 const float* __restrict__ b_lin,
                                                 float* __restrict__ out, int N) {
    int tid = threadIdx.x;
    int swid = (blockIdx.x * blockDim.x + tid) >> 5;
    if (swid >= N) return;
    int lane32 = tid & 31;
    int grp = lane32 >> 4;         // edge group 0/1
    int c16 = lane32 & 15;         // uint index in 16-uint row (features 2*c16, 2*c16+1)
    int dst = swid;
    int start = rowptr[dst], end = rowptr[dst + 1];
    float adv = ad2[dst];

    float m = -3.0e38f;            // finite sentinel (avoids -inf - -inf NaN)
    float acc0 = 0.0f, acc1 = 0.0f, den = 0.0f;
    for (int cb = start; cb < end; cb += 8) {
        int j0 = cb + 4 * grp;
        int e1i = min(j0 + 1, end - 1), e2i = min(j0 + 2, end - 1), e3i = min(j0 + 3, end - 1);
        int j0c = min(j0, end - 1);
        int s0 = col[j0c], s1 = col[e1i], s2 = col[e2i], s3 = col[e3i];
        float l0 = (j0     < end) ? leaky(as2[s0] + adv) : -INFINITY;
        float l1 = (j0 + 1 < end) ? leaky(as2[s1] + adv) : -INFINITY;
        float l2 = (j0 + 2 < end) ? leaky(as2[s2] + adv) : -INFINITY;
        float l3 = (j0 + 3 < end) ? leaky(as2[s3] + adv) : -INFINITY;
        unsigned u0 = h2b[(size_t)s0 * 16 + c16];
        unsigned u1 = h2b[(size_t)s1 * 16 + c16];
        unsigned u2 = h2b[(size_t)s2 * 16 + c16];
        unsigned u3 = h2b[(size_t)s3 * 16 + c16];
        float m4 = fmaxf(fmaxf(l0, l1), fmaxf(l2, l3));
        if (m4 > m) {                       // uniform within 16-lane group
            float sc = __expf(m - m4);
            acc0 *= sc; acc1 *= sc; den *= sc; m = m4;
        }
        float x0 = __expf(l0 - m), x1 = __expf(l1 - m);
        float x2 = __expf(l2 - m), x3 = __expf(l3 - m);
        den += (x0 + x1) + (x2 + x3);
        acc0 += x0 * bf16lo(u0) + x1 * bf16lo(u1) + x2 * bf16lo(u2) + x3 * bf16lo(u3);
        acc1 += x0 * bf16hi(u0) + x1 * bf16hi(u1) + x2 * bf16hi(u2) + x3 * bf16hi(u3);
    }

    // merge the two groups' online states (lane l <-> l^16 holds same c16)
    float mo = __shfl_xor(m, 16);
    float ms = fmaxf(m, mo);
    float sc = __expf(m - ms);
    den *= sc; acc0 *= sc; acc1 *= sc;
    den  += __shfl_xor(den, 16);
    acc0 += __shfl_xor(acc0, 16);
    acc1 += __shfl_xor(acc1, 16);

    float inv = 1.0f / (den + EPS);
    int f0 = c16 * 2;
    float v0 = acc0 * inv + b2[f0];
    float v1 = acc1 * inv + b2[f0 + 1];
    v0 = v0 > 0.0f ? v0 : 0.0f;
    v1 = v1 > 0.0f ? v1 : 0.0f;

    // final linear: dot over 32 features (16 lanes x 2 each)
    float w = v0 * W_lin[f0] + v1 * W_lin[f0 + 1];
    w += __shfl_xor(w, 1); w += __shfl_xor(w, 2);
    w += __shfl_xor(w, 4); w += __shfl_xor(w, 8);
    if (lane32 == 0) out[dst] = w + b_lin[0];
}

extern "C" void kernel_launch(void* const* d_in, const int* in_sizes, int n_in,
                              void* d_out, int out_size, void* d_ws, size_t ws_size,
                              hipStream_t stream) {
    const float* x      = (const float*)d_in[0];
    const int*   ei     = (const int*)d_in[1];
    // d_in[2] = batch (unused)
    const float* W1     = (const float*)d_in[3];
    const float* a_src1 = (const float*)d_in[4];
    const float* a_dst1 = (const float*)d_in[5];
    const float* b1     = (const float*)d_in[6];
    const float* W2     = (const float*)d_in[7];
    const float* a_src2 = (const float*)d_in[8];
    const float* a_dst2 = (const float*)d_in[9];
    const float* b2     = (const float*)d_in[10];
    const float* W_lin  = (const float*)d_in[11];
    const float* b_lin  = (const float*)d_in[12];
    float* out = (float*)d_out;

    const int N = in_sizes[0] / 64;
    const int E = in_sizes[1] / 2;
    const int T = E + N;               // total edges incl. self-loops
    const int NB = (N + 255) >> 8;     // buckets of 256 dst nodes (<=512)

    // workspace layout
    float* ws = (float*)d_ws;
    size_t off = 0;
    float* h1reg = ws + off; off += (size_t)N * 128;  // h1bf uses N*64 uints; spare upper half hosts binned
    float* out1 = ws + off; off += (size_t)N * 128;
    float* as1  = ws + off; off += (size_t)N * 4;
    float* ad1  = ws + off; off += (size_t)N * 4;
    float* as2  = ws + off; off += (size_t)N;
    float* ad2  = ws + off; off += (size_t)N;
    int* rowptr    = (int*)(ws + off); off += (size_t)N + 4;
    int* bucketptr = (int*)(ws + off); off += 1024;   // NB+1 <= 513
    int* bhist     = (int*)(ws + off); off += 512;
    int* bcursor   = (int*)(ws + off); off += 512;
    int* colarr    = (int*)(ws + off); off += (size_t)T;
    unsigned* h1bf = (unsigned*)h1reg;                       // N*64 uints (bf16x2)
    unsigned* h2bf = (unsigned*)h1reg;                       // reuses h1reg after gather1
    unsigned* binned = (unsigned*)h1reg + (size_t)N * 64;    // T uints in h1reg's spare half

    const int B = 256;
    auto blocks = [](size_t t, int b) { return (unsigned)((t + b - 1) / b); };

    // bucket-binned CSR build
    hipMemsetAsync(bhist, 0, 512 * sizeof(int), stream);
    k_binhist<<<256, 256, 0, stream>>>(ei, bhist, E, N);
    k_binscan<<<1, 512, 0, stream>>>(bhist, bucketptr, bcursor, rowptr, NB, N, T);
    k_binfill<<<blocks(T, BF_CHUNK), 512, 0, stream>>>(ei, bcursor, binned, E, N);

    // fat kernel: bucketfill (CSR tail) + gemm1 (independent) overlapped
    k_bucketfill_gemm1<<<(unsigned)(NB + (N + 31) / 32), B, 0, stream>>>(
        binned, bucketptr, rowptr, colarr,
        x, W1, a_src1, a_dst1, h1bf, as1, ad1, N, NB);

    // layer 1 gather (R6-best: two-pass, 8 edges/iter)
    k_gather1<<<(unsigned)((N + 3) / 4), B, 0, stream>>>(rowptr, colarr, as1, ad1, h1bf, b1, out1, N);

    // layer 2 (+ fused final linear)
    k_gemm2  <<<(unsigned)((N + 127) / 128), B, 0, stream>>>(out1, W2, a_src2, a_dst2, h2bf, as2, ad2, N);
    k_gather2<<<blocks((size_t)N * 32, B), B, 0, stream>>>(rowptr, colarr, as2, ad2,
                                                           h2bf, b2, W_lin, b_lin, out, N);
}

// Round 9
// 317.798 us; speedup vs baseline: 1.0253x; 1.0056x over previous
//
#include <hip/hip_runtime.h>
#include <math.h>

#define NEG_SLOPE 0.2f
#define EPS 1e-16f

__device__ inline float leaky(float v) {
    return v >= 0.0f ? v : NEG_SLOPE * v;
}

// pack two floats into bf16x2 (RNE), low half = first arg
__device__ inline unsigned bf16pack2(float a, float b) {
    unsigned ua = __float_as_uint(a);
    unsigned ub = __float_as_uint(b);
    ua = (ua + 0x7FFFu + ((ua >> 16) & 1u)) >> 16;
    ub = (ub + 0x7FFFu + ((ub >> 16) & 1u)) >> 16;
    return ua | (ub << 16);
}

__device__ inline float bf16lo(unsigned u) { return __uint_as_float(u << 16); }
__device__ inline float bf16hi(unsigned u) { return __uint_as_float(u & 0xFFFF0000u); }

// ================= bucket-binned CSR build =================
// Buckets of 256 dst nodes. Packed binned entry: (src << 8) | (dst & 255).
// Requires src < 2^24 and nbuckets <= 512 (N <= 131072).

// per-block LDS-aggregated bucket histogram over all T = E+N entries
__global__ __launch_bounds__(256) void k_binhist(const int* __restrict__ ei, int* __restrict__ bhist,
                                                 int E, int N) {
    __shared__ int sh[512];
    int tid = threadIdx.x;
    sh[tid] = 0; sh[tid + 256] = 0;
    __syncthreads();
    int T = E + N;
    int stride = gridDim.x * 256;
    for (int t = blockIdx.x * 256 + tid; t < T; t += stride) {
        int d = (t < E) ? ei[E + t] : (t - E);
        atomicAdd(&sh[d >> 8], 1);
    }
    __syncthreads();
    int c0 = sh[tid];       if (c0) atomicAdd(&bhist[tid], c0);
    int c1 = sh[tid + 256]; if (c1) atomicAdd(&bhist[tid + 256], c1);
}

// one-block exclusive scan of bucket counts -> bucketptr, bcursor; rowptr[N]=T
__global__ __launch_bounds__(512) void k_binscan(const int* __restrict__ bhist,
                                                 int* __restrict__ bucketptr,
                                                 int* __restrict__ bcursor,
                                                 int* __restrict__ rowptr,
                                                 int nb, int N, int T) {
    __shared__ int s[512];
    int tid = threadIdx.x;
    int v = (tid < nb) ? bhist[tid] : 0;
    s[tid] = v;
    __syncthreads();
#pragma unroll
    for (int off = 1; off < 512; off <<= 1) {
        int t = (tid >= off) ? s[tid - off] : 0;
        __syncthreads();
        s[tid] += t;
        __syncthreads();
    }
    int excl = s[tid] - v;
    if (tid < nb) { bucketptr[tid] = excl; bcursor[tid] = excl; }
    else          { bcursor[tid] = 0; }
    if (tid == 0) { bucketptr[nb] = T; rowptr[N] = T; }
}

// bin edges into bucket-contiguous regions (one atomic reservation per
// bucket per block; packed writes into reserved runs -> L2-coalesced).
#define BF_CHUNK 8192
__global__ __launch_bounds__(512) void k_binfill(const int* __restrict__ ei,
                                                 int* __restrict__ bcursor,
                                                 unsigned* __restrict__ binned,
                                                 int E, int N) {
    __shared__ int h[512], lc[512], gb[512];
    int tid = threadIdx.x;
    int T = E + N;
    int base = blockIdx.x * BF_CHUNK;
    int n = T - base; if (n > BF_CHUNK) n = BF_CHUNK;
    h[tid] = 0; lc[tid] = 0;
    __syncthreads();
    for (int i = tid; i < n; i += 512) {
        int t = base + i;
        int d = (t < E) ? ei[E + t] : (t - E);
        atomicAdd(&h[d >> 8], 1);
    }
    __syncthreads();
    if (h[tid] > 0) gb[tid] = atomicAdd(&bcursor[tid], h[tid]);
    __syncthreads();
    for (int i = tid; i < n; i += 512) {
        int t = base + i;
        int s, d;
        if (t < E) { s = ei[t]; d = ei[E + t]; } else { s = d = t - E; }
        int b = d >> 8;
        int slot = atomicAdd(&lc[b], 1);
        binned[gb[b] + slot] = ((unsigned)s << 8) | (unsigned)(d & 255);
    }
}

// ---------------- fat kernel: bucketfill (blocks < NB) + gemm1 (rest) ------
__global__ __launch_bounds__(256) void k_bucketfill_gemm1(
        const unsigned* __restrict__ binned, const int* __restrict__ bucketptr,
        int* __restrict__ rowptr, int* __restrict__ col,
        const float* __restrict__ x, const float* __restrict__ W1,
        const float* __restrict__ a_src, const float* __restrict__ a_dst,
        unsigned* __restrict__ h1bf, float* __restrict__ as1,
        float* __restrict__ ad1, int N, int nbuckets) {
    __shared__ float smem[64 * 128 + 32 * 64];   // 40 KB, aliased by role
    int tid = threadIdx.x;

    if ((int)blockIdx.x < nbuckets) {
        // ---- bucketfill role (256 threads) ----
        int* h  = (int*)smem;
        int* o  = h + 256;
        int* lc = o + 256;
        int b = blockIdx.x;
        int gs = bucketptr[b], ge = bucketptr[b + 1];
        h[tid] = 0; lc[tid] = 0;
        __syncthreads();
        for (int j = gs + tid; j < ge; j += 256)
            atomicAdd(&h[binned[j] & 255], 1);
        __syncthreads();
        int v = h[tid];
        o[tid] = v;
        __syncthreads();
#pragma unroll
        for (int off = 1; off < 256; off <<= 1) {
            int t = (tid >= off) ? o[tid - off] : 0;
            __syncthreads();
            o[tid] += t;
            __syncthreads();
        }
        int excl = o[tid] - v;
        int dst0 = b << 8;
        if (dst0 + tid < N) rowptr[dst0 + tid] = gs + excl;
        o[tid] = excl;
        __syncthreads();
        for (int j = gs + tid; j < ge; j += 256) {
            unsigned pv = binned[j];
            int d = pv & 255;
            int s = (int)(pv >> 8);
            int slot = atomicAdd(&lc[d], 1);
            col[gs + o[d] + slot] = s;
        }
        return;
    }

    // ---- gemm1 role ----
    float* sW = smem;                 // [64][128]
    float* sX = smem + 64 * 128;      // [32][64]
    int block_r0 = ((int)blockIdx.x - nbuckets) * 32;

    {
        float4* dst = (float4*)sW;
        const float4* srcp = (const float4*)W1;
#pragma unroll
        for (int i = 0; i < 8; ++i) dst[tid + 256 * i] = srcp[tid + 256 * i];
    }
    {
        float4* dst = (float4*)sX;
#pragma unroll
        for (int i = 0; i < 2; ++i) {
            int idx = tid + 256 * i;
            int r = idx >> 4;            // 0..31
            int c = idx & 15;            // float4 within row
            int gr = min(block_r0 + r, N - 1);
            dst[idx] = ((const float4*)(x + (size_t)gr * 64))[c];
        }
    }
    __syncthreads();

    int c4 = tid & 31;             // col quad 0..31
    int rq = tid >> 5;             // row quad 0..7
    int r0 = block_r0 + rq * 4;
    const float4* wS = (const float4*)sW;   // [64][32]
    const float4* xS = (const float4*)sX;   // [32][16]

    float4 acc0 = {0,0,0,0}, acc1 = {0,0,0,0}, acc2 = {0,0,0,0}, acc3 = {0,0,0,0};
#pragma unroll 2
    for (int k4 = 0; k4 < 16; ++k4) {
        float4 xa = xS[(rq * 4 + 0) * 16 + k4];
        float4 xb = xS[(rq * 4 + 1) * 16 + k4];
        float4 xc = xS[(rq * 4 + 2) * 16 + k4];
        float4 xd = xS[(rq * 4 + 3) * 16 + k4];
        float4 w0 = wS[(k4 * 4 + 0) * 32 + c4];
        float4 w1 = wS[(k4 * 4 + 1) * 32 + c4];
        float4 w2 = wS[(k4 * 4 + 2) * 32 + c4];
        float4 w3 = wS[(k4 * 4 + 3) * 32 + c4];
        acc0.x += xa.x*w0.x + xa.y*w1.x + xa.z*w2.x + xa.w*w3.x;
        acc0.y += xa.x*w0.y + xa.y*w1.y + xa.z*w2.y + xa.w*w3.y;
        acc0.z += xa.x*w0.z + xa.y*w1.z + xa.z*w2.z + xa.w*w3.z;
        acc0.w += xa.x*w0.w + xa.y*w1.w + xa.z*w2.w + xa.w*w3.w;
        acc1.x += xb.x*w0.x + xb.y*w1.x + xb.z*w2.x + xb.w*w3.x;
        acc1.y += xb.x*w0.y + xb.y*w1.y + xb.z*w2.y + xb.w*w3.y;
        acc1.z += xb.x*w0.z + xb.y*w1.z + xb.z*w2.z + xb.w*w3.z;
        acc1.w += xb.x*w0.w + xb.y*w1.w + xb.z*w2.w + xb.w*w3.w;
        acc2.x += xc.x*w0.x + xc.y*w1.x + xc.z*w2.x + xc.w*w3.x;
        acc2.y += xc.x*w0.y + xc.y*w1.y + xc.z*w2.y + xc.w*w3.y;
        acc2.z += xc.x*w0.z + xc.y*w1.z + xc.z*w2.z + xc.w*w3.z;
        acc2.w += xc.x*w0.w + xc.y*w1.w + xc.z*w2.w + xc.w*w3.w;
        acc3.x += xd.x*w0.x + xd.y*w1.x + xd.z*w2.x + xd.w*w3.x;
        acc3.y += xd.x*w0.y + xd.y*w1.y + xd.z*w2.y + xd.w*w3.y;
        acc3.z += xd.x*w0.z + xd.y*w1.z + xd.z*w2.z + xd.w*w3.z;
        acc3.w += xd.x*w0.w + xd.y*w1.w + xd.z*w2.w + xd.w*w3.w;
    }

    uint2 p0 = { bf16pack2(acc0.x, acc0.y), bf16pack2(acc0.z, acc0.w) };
    uint2 p1 = { bf16pack2(acc1.x, acc1.y), bf16pack2(acc1.z, acc1.w) };
    uint2 p2 = { bf16pack2(acc2.x, acc2.y), bf16pack2(acc2.z, acc2.w) };
    uint2 p3 = { bf16pack2(acc3.x, acc3.y), bf16pack2(acc3.z, acc3.w) };
    uint2* hb = (uint2*)h1bf;
    if (r0 + 0 < N) hb[(size_t)(r0 + 0) * 32 + c4] = p0;
    if (r0 + 1 < N) hb[(size_t)(r0 + 1) * 32 + c4] = p1;
    if (r0 + 2 < N) hb[(size_t)(r0 + 2) * 32 + c4] = p2;
    if (r0 + 3 < N) hb[(size_t)(r0 + 3) * 32 + c4] = p3;

    float4 av = ((const float4*)a_src)[c4];
    float4 dv = ((const float4*)a_dst)[c4];
    float s0 = acc0.x*av.x + acc0.y*av.y + acc0.z*av.z + acc0.w*av.w;
    float s1 = acc1.x*av.x + acc1.y*av.y + acc1.z*av.z + acc1.w*av.w;
    float s2 = acc2.x*av.x + acc2.y*av.y + acc2.z*av.z + acc2.w*av.w;
    float s3 = acc3.x*av.x + acc3.y*av.y + acc3.z*av.z + acc3.w*av.w;
    float d0 = acc0.x*dv.x + acc0.y*dv.y + acc0.z*dv.z + acc0.w*dv.w;
    float d1 = acc1.x*dv.x + acc1.y*dv.y + acc1.z*dv.z + acc1.w*dv.w;
    float d2 = acc2.x*dv.x + acc2.y*dv.y + acc2.z*dv.z + acc2.w*dv.w;
    float d3 = acc3.x*dv.x + acc3.y*dv.y + acc3.z*dv.z + acc3.w*dv.w;
#pragma unroll
    for (int off = 1; off < 8; off <<= 1) {
        s0 += __shfl_xor(s0, off); s1 += __shfl_xor(s1, off);
        s2 += __shfl_xor(s2, off); s3 += __shfl_xor(s3, off);
        d0 += __shfl_xor(d0, off); d1 += __shfl_xor(d1, off);
        d2 += __shfl_xor(d2, off); d3 += __shfl_xor(d3, off);
    }
    if ((c4 & 7) == 0) {
        int h = c4 >> 3;
        if (r0 + 0 < N) { as1[(r0 + 0) * 4 + h] = s0; ad1[(r0 + 0) * 4 + h] = d0; }
        if (r0 + 1 < N) { as1[(r0 + 1) * 4 + h] = s1; ad1[(r0 + 1) * 4 + h] = d1; }
        if (r0 + 2 < N) { as1[(r0 + 2) * 4 + h] = s2; ad1[(r0 + 2) * 4 + h] = d2; }
        if (r0 + 3 < N) { as1[(r0 + 3) * 4 + h] = s3; ad1[(r0 + 3) * 4 + h] = d3; }
    }
}

// ---------------- layer 1 fused gather: two-pass softmax, 8 edges/iter -----
// (R6 best-measured form) — output out1 now packed bf16 (N x 64 uints).
__global__ __launch_bounds__(256) void k_gather1(const int* __restrict__ rowptr,
                                                 const int* __restrict__ col,
                                                 const float* __restrict__ as1,
                                                 const float* __restrict__ ad1,
                                                 const unsigned* __restrict__ h1bf,
                                                 const float* __restrict__ b1,
                                                 unsigned* __restrict__ out1b, int N) {
    __shared__ float s_ex[4][64 * 4];   // [wave][edge*4+head]
    __shared__ int   s_src[4][64];      // [wave][edge]
    int tid = threadIdx.x;
    int wv = tid >> 6;
    int lane = tid & 63;
    int dst = blockIdx.x * 4 + wv;
    if (dst >= N) return;
    int start = rowptr[dst], end = rowptr[dst + 1];
    float4 ad = *(const float4*)(ad1 + (size_t)dst * 4);

    // phase A: per-head max (lane-per-edge, strided)
    float m0 = -INFINITY, m1 = -INFINITY, m2 = -INFINITY, m3 = -INFINITY;
    for (int j = start + lane; j < end; j += 64) {
        int src = col[j];
        float4 a = *(const float4*)(as1 + (size_t)src * 4);
        m0 = fmaxf(m0, leaky(a.x + ad.x));
        m1 = fmaxf(m1, leaky(a.y + ad.y));
        m2 = fmaxf(m2, leaky(a.z + ad.z));
        m3 = fmaxf(m3, leaky(a.w + ad.w));
    }
#pragma unroll
    for (int off = 32; off; off >>= 1) {
        m0 = fmaxf(m0, __shfl_xor(m0, off));
        m1 = fmaxf(m1, __shfl_xor(m1, off));
        m2 = fmaxf(m2, __shfl_xor(m2, off));
        m3 = fmaxf(m3, __shfl_xor(m3, off));
    }

    int sub = lane >> 4;           // edge slot 0..3
    int fl = lane & 15;            // uint4 index (features fl*8 .. fl*8+7)
    int hh = fl >> 2;              // head of this lane's features
    const uint4* hb4 = (const uint4*)h1bf;
    float* exw = s_ex[wv];
    int* srw = s_src[wv];

    float d0 = 0, d1 = 0, d2 = 0, d3 = 0;            // softmax denominators
    float4 accA = {0,0,0,0}, accB = {0,0,0,0};       // 8 features per lane

    for (int base = start; base < end; base += 64) {
        int nedge = end - base; if (nedge > 64) nedge = 64;
        // phase B: lane-per-edge exp (inactive lanes pad with ex=0, src=0)
        float e0 = 0, e1 = 0, e2 = 0, e3 = 0;
        int src = 0;
        if (lane < nedge) {
            src = col[base + lane];
            float4 a = *(const float4*)(as1 + (size_t)src * 4);
            e0 = __expf(leaky(a.x + ad.x) - m0);
            e1 = __expf(leaky(a.y + ad.y) - m1);
            e2 = __expf(leaky(a.z + ad.z) - m2);
            e3 = __expf(leaky(a.w + ad.w) - m3);
            d0 += e0; d1 += e1; d2 += e2; d3 += e3;
        }
        asm volatile("s_waitcnt lgkmcnt(0)" ::: "memory");  // prior chunk's reads done
        srw[lane] = src;
        float4 ev = {e0, e1, e2, e3};
        *(float4*)(exw + lane * 4) = ev;
        asm volatile("s_waitcnt lgkmcnt(0)" ::: "memory");  // writes visible wave-wide
        // phase C: 8 edges per iteration, two independent gathers per lane
        for (int e = 0; e < nedge; e += 8) {
            int ea = e + sub;                 // <= 59
            int eb = e + 4 + sub;             // <= 63
            int sa = srw[ea];
            int sb = srw[eb];
            float xa = exw[ea * 4 + hh];
            float xb = exw[eb * 4 + hh];
            uint4 ua = hb4[(size_t)sa * 16 + fl];
            uint4 ub = hb4[(size_t)sb * 16 + fl];
            accA.x += xa * bf16lo(ua.x) + xb * bf16lo(ub.x);
            accA.y += xa * bf16hi(ua.x) + xb * bf16hi(ub.x);
            accA.z += xa * bf16lo(ua.y) + xb * bf16lo(ub.y);
            accA.w += xa * bf16hi(ua.y) + xb * bf16hi(ub.y);
            accB.x += xa * bf16lo(ua.z) + xb * bf16lo(ub.z);
            accB.y += xa * bf16hi(ua.z) + xb * bf16hi(ub.z);
            accB.z += xa * bf16lo(ua.w) + xb * bf16lo(ub.w);
            accB.w += xa * bf16hi(ua.w) + xb * bf16hi(ub.w);
        }
    }

    // reduce denominators across lanes
#pragma unroll
    for (int off = 32; off; off >>= 1) {
        d0 += __shfl_xor(d0, off); d1 += __shfl_xor(d1, off);
        d2 += __shfl_xor(d2, off); d3 += __shfl_xor(d3, off);
    }
    // combine the 4 edge sub-slots
#pragma unroll
    for (int off = 16; off <= 32; off <<= 1) {
        accA.x += __shfl_xor(accA.x, off); accA.y += __shfl_xor(accA.y, off);
        accA.z += __shfl_xor(accA.z, off); accA.w += __shfl_xor(accA.w, off);
        accB.x += __shfl_xor(accB.x, off); accB.y += __shfl_xor(accB.y, off);
        accB.z += __shfl_xor(accB.z, off); accB.w += __shfl_xor(accB.w, off);
    }

    if (lane < 16) {
        float denh = (hh == 0) ? d0 : (hh == 1) ? d1 : (hh == 2) ? d2 : d3;
        float inv = 1.0f / (denh + EPS);
        int f0 = lane * 8;
        float4 ba = *(const float4*)(b1 + f0);
        float4 bb = *(const float4*)(b1 + f0 + 4);
        float4 oa, ob;
        oa.x = accA.x * inv + ba.x; oa.x = oa.x > 0.0f ? oa.x : 0.0f;
        oa.y = accA.y * inv + ba.y; oa.y = oa.y > 0.0f ? oa.y : 0.0f;
        oa.z = accA.z * inv + ba.z; oa.z = oa.z > 0.0f ? oa.z : 0.0f;
        oa.w = accA.w * inv + ba.w; oa.w = oa.w > 0.0f ? oa.w : 0.0f;
        ob.x = accB.x * inv + bb.x; ob.x = ob.x > 0.0f ? ob.x : 0.0f;
        ob.y = accB.y * inv + bb.y; ob.y = ob.y > 0.0f ? ob.y : 0.0f;
        ob.z = accB.z * inv + bb.z; ob.z = ob.z > 0.0f ? ob.z : 0.0f;
        ob.w = accB.w * inv + bb.w; ob.w = ob.w > 0.0f ? ob.w : 0.0f;
        uint4 pk = { bf16pack2(oa.x, oa.y), bf16pack2(oa.z, oa.w),
                     bf16pack2(ob.x, ob.y), bf16pack2(ob.z, ob.w) };
        *(uint4*)(out1b + (size_t)dst * 64 + lane * 4) = pk;
    }
}

// ---------------- layer 2 GEMM + alpha (bf16 out1 in, bf16 h2 out) ---------
__global__ __launch_bounds__(256) void k_gemm2(const unsigned* __restrict__ out1b,
                                               const float* __restrict__ W2,
                                               const float* __restrict__ a_src,
                                               const float* __restrict__ a_dst,
                                               unsigned* __restrict__ h2bf,
                                               float* __restrict__ as2,
                                               float* __restrict__ ad2, int N) {
    __shared__ float sW[128 * 32];   // 16 KB, [k][col]
    int tid = threadIdx.x;

    {
        float4* dst = (float4*)sW;
        const float4* srcp = (const float4*)W2;
#pragma unroll
        for (int i = 0; i < 4; ++i) dst[tid + 256 * i] = srcp[tid + 256 * i];
    }
    __syncthreads();

    int c4 = tid & 7;              // col quad 0..7
    int rq = tid >> 3;             // row quad 0..31
    int r0 = blockIdx.x * 128 + rq * 4;
    if (r0 >= N) return;
    const unsigned* xr0 = out1b + (size_t)min(r0 + 0, N - 1) * 64;
    const unsigned* xr1 = out1b + (size_t)min(r0 + 1, N - 1) * 64;
    const unsigned* xr2 = out1b + (size_t)min(r0 + 2, N - 1) * 64;
    const unsigned* xr3 = out1b + (size_t)min(r0 + 3, N - 1) * 64;
    const float4* wS = (const float4*)sW;   // [128][8]

    float4 acc0 = {0,0,0,0}, acc1 = {0,0,0,0}, acc2 = {0,0,0,0}, acc3 = {0,0,0,0};
    // k8 step: load uint4 = 8 bf16 features per row; two 4-feature halves
    for (int k8 = 0; k8 < 16; ++k8) {
        uint4 ua = *(const uint4*)(xr0 + k8 * 4);
        uint4 ub = *(const uint4*)(xr1 + k8 * 4);
        uint4 uc = *(const uint4*)(xr2 + k8 * 4);
        uint4 ud = *(const uint4*)(xr3 + k8 * 4);
        // half 1: features 8*k8 .. 8*k8+3
        {
            float4 w0 = wS[(k8 * 8 + 0) * 8 + c4];
            float4 w1 = wS[(k8 * 8 + 1) * 8 + c4];
            float4 w2 = wS[(k8 * 8 + 2) * 8 + c4];
            float4 w3 = wS[(k8 * 8 + 3) * 8 + c4];
            float a0 = bf16lo(ua.x), a1 = bf16hi(ua.x), a2 = bf16lo(ua.y), a3 = bf16hi(ua.y);
            float b0 = bf16lo(ub.x), b1v = bf16hi(ub.x), b2v = bf16lo(ub.y), b3 = bf16hi(ub.y);
            float c0 = bf16lo(uc.x), c1 = bf16hi(uc.x), c2 = bf16lo(uc.y), c3 = bf16hi(uc.y);
            float e0 = bf16lo(ud.x), e1 = bf16hi(ud.x), e2 = bf16lo(ud.y), e3 = bf16hi(ud.y);
            acc0.x += a0*w0.x + a1*w1.x + a2*w2.x + a3*w3.x;
            acc0.y += a0*w0.y + a1*w1.y + a2*w2.y + a3*w3.y;
            acc0.z += a0*w0.z + a1*w1.z + a2*w2.z + a3*w3.z;
            acc0.w += a0*w0.w + a1*w1.w + a2*w2.w + a3*w3.w;
            acc1.x += b0*w0.x + b1v*w1.x + b2v*w2.x + b3*w3.x;
            acc1.y += b0*w0.y + b1v*w1.y + b2v*w2.y + b3*w3.y;
            acc1.z += b0*w0.z + b1v*w1.z + b2v*w2.z + b3*w3.z;
            acc1.w += b0*w0.w + b1v*w1.w + b2v*w2.w + b3*w3.w;
            acc2.x += c0*w0.x + c1*w1.x + c2*w2.x + c3*w3.x;
            acc2.y += c0*w0.y + c1*w1.y + c2*w2.y + c3*w3.y;
            acc2.z += c0*w0.z + c1*w1.z + c2*w2.z + c3*w3.z;
            acc2.w += c0*w0.w + c1*w1.w + c2*w2.w + c3*w3.w;
            acc3.x += e0*w0.x + e1*w1.x + e2*w2.x + e3*w3.x;
            acc3.y += e0*w0.y + e1*w1.y + e2*w2.y + e3*w3.y;
            acc3.z += e0*w0.z + e1*w1.z + e2*w2.z + e3*w3.z;
            acc3.w += e0*w0.w + e1*w1.w + e2*w2.w + e3*w3.w;
        }
        // half 2: features 8*k8+4 .. 8*k8+7
        {
            float4 w0 = wS[(k8 * 8 + 4) * 8 + c4];
            float4 w1 = wS[(k8 * 8 + 5) * 8 + c4];
            float4 w2 = wS[(k8 * 8 + 6) * 8 + c4];
            float4 w3 = wS[(k8 * 8 + 7) * 8 + c4];
            float a0 = bf16lo(ua.z), a1 = bf16hi(ua.z), a2 = bf16lo(ua.w), a3 = bf16hi(ua.w);
            float b0 = bf16lo(ub.z), b1v = bf16hi(ub.z), b2v = bf16lo(ub.w), b3 = bf16hi(ub.w);
            float c0 = bf16lo(uc.z), c1 = bf16hi(uc.z), c2 = bf16lo(uc.w), c3 = bf16hi(uc.w);
            float e0 = bf16lo(ud.z), e1 = bf16hi(ud.z), e2 = bf16lo(ud.w), e3 = bf16hi(ud.w);
            acc0.x += a0*w0.x + a1*w1.x + a2*w2.x + a3*w3.x;
            acc0.y += a0*w0.y + a1*w1.y + a2*w2.y + a3*w3.y;
            acc0.z += a0*w0.z + a1*w1.z + a2*w2.z + a3*w3.z;
            acc0.w += a0*w0.w + a1*w1.w + a2*w2.w + a3*w3.w;
            acc1.x += b0*w0.x + b1v*w1.x + b2v*w2.x + b3*w3.x;
            acc1.y += b0*w0.y + b1v*w1.y + b2v*w2.y + b3*w3.y;
            acc1.z += b0*w0.z + b1v*w1.z + b2v*w2.z + b3*w3.z;
            acc1.w += b0*w0.w + b1v*w1.w + b2v*w2.w + b3*w3.w;
            acc2.x += c0*w0.x + c1*w1.x + c2*w2.x + c3*w3.x;
            acc2.y += c0*w0.y + c1*w1.y + c2*w2.y + c3*w3.y;
            acc2.z += c0*w0.z + c1*w1.z + c2*w2.z + c3*w3.z;
            acc2.w += c0*w0.w + c1*w1.w + c2*w2.w + c3*w3.w;
            acc3.x += e0*w0.x + e1*w1.x + e2*w2.x + e3*w3.x;
            acc3.y += e0*w0.y + e1*w1.y + e2*w2.y + e3*w3.y;
            acc3.z += e0*w0.z + e1*w1.z + e2*w2.z + e3*w3.z;
            acc3.w += e0*w0.w + e1*w1.w + e2*w2.w + e3*w3.w;
        }
    }

    uint2 q0 = { bf16pack2(acc0.x, acc0.y), bf16pack2(acc0.z, acc0.w) };
    uint2 q1 = { bf16pack2(acc1.x, acc1.y), bf16pack2(acc1.z, acc1.w) };
    uint2 q2 = { bf16pack2(acc2.x, acc2.y), bf16pack2(acc2.z, acc2.w) };
    uint2 q3 = { bf16pack2(acc3.x, acc3.y), bf16pack2(acc3.z, acc3.w) };
    uint2* hb = (uint2*)h2bf;
    if (r0 + 0 < N) hb[(size_t)(r0 + 0) * 8 + c4] = q0;
    if (r0 + 1 < N) hb[(size_t)(r0 + 1) * 8 + c4] = q1;
    if (r0 + 2 < N) hb[(size_t)(r0 + 2) * 8 + c4] = q2;
    if (r0 + 3 < N) hb[(size_t)(r0 + 3) * 8 + c4] = q3;

    float4 av = ((const float4*)a_src)[c4];
    float4 dv = ((const float4*)a_dst)[c4];
    float s0 = acc0.x*av.x + acc0.y*av.y + acc0.z*av.z + acc0.w*av.w;
    float s1 = acc1.x*av.x + acc1.y*av.y + acc1.z*av.z + acc1.w*av.w;
    float s2 = acc2.x*av.x + acc2.y*av.y + acc2.z*av.z + acc2.w*av.w;
    float s3 = acc3.x*av.x + acc3.y*av.y + acc3.z*av.z + acc3.w*av.w;
    float d0 = acc0.x*dv.x + acc0.y*dv.y + acc0.z*dv.z + acc0.w*dv.w;
    float d1 = acc1.x*dv.x + acc1.y*dv.y + acc1.z*dv.z + acc1.w*dv.w;
    float d2 = acc2.x*dv.x + acc2.y*dv.y + acc2.z*dv.z + acc2.w*dv.w;
    float d3 = acc3.x*dv.x + acc3.y*dv.y + acc3.z*dv.z + acc3.w*dv.w;
#pragma unroll
    for (int off = 1; off < 8; off <<= 1) {
        s0 += __shfl_xor(s0, off); s1 += __shfl_xor(s1, off);
        s2 += __shfl_xor(s2, off); s3 += __shfl_xor(s3, off);
        d0 += __shfl_xor(d0, off); d1 += __shfl_xor(d1, off);
        d2 += __shfl_xor(d2, off); d3 += __shfl_xor(d3, off);
    }
    if (c4 == 0) {
        if (r0 + 0 < N) { as2[r0 + 0] = s0; ad2[r0 + 0] = d0; }
        if (r0 + 1 < N) { as2[r0 + 1] = s1; ad2[r0 + 1] = d1; }
        if (r0 + 2 < N) { as2[r0 + 2] = s2; ad2[r0 + 2] = d2; }
        if (r0 + 3 < N) { as2[r0 + 3] = s3; ad2[r0 + 3] = d3; }
    }
}

// ---------------- layer 2 fused gather + final linear ----------------------
// Half-wave per dst split into TWO 16-lane groups (R8 best-measured form).
__global__ __launch_bounds__(256) void k_gather2(const int* __restrict__ rowptr,
                                                 const int* __restrict__ col,
                                                 const float* __restrict__ as2,
                                                 const float* __restrict__ ad2,
                                                 const unsigned* __restrict__ h2b,
                                                 const float* __restrict__ b2,
                                                 const float* __restrict__ W_lin,
                                                 const float* __restrict__ b_lin,
                                                 float* __restrict__ out, int N) {
    int tid = threadIdx.x;
    int swid = (blockIdx.x * blockDim.x + tid) >> 5;
    if (swid >= N) return;
    int lane32 = tid & 31;
    int grp = lane32 >> 4;         // edge group 0/1
    int c16 = lane32 & 15;         // uint index in 16-uint row (features 2*c16, 2*c16+1)
    int dst = swid;
    int start = rowptr[dst], end = rowptr[dst + 1];
    float adv = ad2[dst];

    float m = -3.0e38f;            // finite sentinel (avoids -inf - -inf NaN)
    float acc0 = 0.0f, acc1 = 0.0f, den = 0.0f;
    for (int cb = start; cb < end; cb += 8) {
        int j0 = cb + 4 * grp;
        int e1i = min(j0 + 1, end - 1), e2i = min(j0 + 2, end - 1), e3i = min(j0 + 3, end - 1);
        int j0c = min(j0, end - 1);
        int s0 = col[j0c], s1 = col[e1i], s2 = col[e2i], s3 = col[e3i];
        float l0 = (j0     < end) ? leaky(as2[s0] + adv) : -INFINITY;
        float l1 = (j0 + 1 < end) ? leaky(as2[s1] + adv) : -INFINITY;
        float l2 = (j0 + 2 < end) ? leaky(as2[s2] + adv) : -INFINITY;
        float l3 = (j0 + 3 < end) ? leaky(as2[s3] + adv) : -INFINITY;
        unsigned u0 = h2b[(size_t)s0 * 16 + c16];
        unsigned u1 = h2b[(size_t)s1 * 16 + c16];
        unsigned u2 = h2b[(size_t)s2 * 16 + c16];
        unsigned u3 = h2b[(size_t)s3 * 16 + c16];
        float m4 = fmaxf(fmaxf(l0, l1), fmaxf(l2, l3));
        if (m4 > m) {                       // uniform within 16-lane group
            float sc = __expf(m - m4);
            acc0 *= sc; acc1 *= sc; den *= sc; m = m4;
        }
        float x0 = __expf(l0 - m), x1 = __expf(l1 - m);
        float x2 = __expf(l2 - m), x3 = __expf(l3 - m);
        den += (x0 + x1) + (x2 + x3);
        acc0 += x0 * bf16lo(u0) + x1 * bf16lo(u1) + x2 * bf16lo(u2) + x3 * bf16lo(u3);
        acc1 += x0 * bf16hi(u0) + x1 * bf16hi(u1) + x2 * bf16hi(u2) + x3 * bf16hi(u3);
    }

    // merge the two groups' online states (lane l <-> l^16 holds same c16)
    float mo = __shfl_xor(m, 16);
    float ms = fmaxf(m, mo);
    float sc = __expf(m - ms);
    den *= sc; acc0 *= sc; acc1 *= sc;
    den  += __shfl_xor(den, 16);
    acc0 += __shfl_xor(acc0, 16);
    acc1 += __shfl_xor(acc1, 16);

    float inv = 1.0f / (den + EPS);
    int f0 = c16 * 2;
    float v0 = acc0 * inv + b2[f0];
    float v1 = acc1 * inv + b2[f0 + 1];
    v0 = v0 > 0.0f ? v0 : 0.0f;
    v1 = v1 > 0.0f ? v1 : 0.0f;

    // final linear: dot over 32 features (16 lanes x 2 each)
    float w = v0 * W_lin[f0] + v1 * W_lin[f0 + 1];
    w += __shfl_xor(w, 1); w += __shfl_xor(w, 2);
    w += __shfl_xor(w, 4); w += __shfl_xor(w, 8);
    if (lane32 == 0) out[dst] = w + b_lin[0];
}

extern "C" void kernel_launch(void* const* d_in, const int* in_sizes, int n_in,
                              void* d_out, int out_size, void* d_ws, size_t ws_size,
                              hipStream_t stream) {
    const float* x      = (const float*)d_in[0];
    const int*   ei     = (const int*)d_in[1];
    // d_in[2] = batch (unused)
    const float* W1     = (const float*)d_in[3];
    const float* a_src1 = (const float*)d_in[4];
    const float* a_dst1 = (const float*)d_in[5];
    const float* b1     = (const float*)d_in[6];
    const float* W2     = (const float*)d_in[7];
    const float* a_src2 = (const float*)d_in[8];
    const float* a_dst2 = (const float*)d_in[9];
    const float* b2     = (const float*)d_in[10];
    const float* W_lin  = (const float*)d_in[11];
    const float* b_lin  = (const float*)d_in[12];
    float* out = (float*)d_out;

    const int N = in_sizes[0] / 64;
    const int E = in_sizes[1] / 2;
    const int T = E + N;               // total edges incl. self-loops
    const int NB = (N + 255) >> 8;     // buckets of 256 dst nodes (<=512)

    // workspace layout
    float* ws = (float*)d_ws;
    size_t off = 0;
    float* h1reg = ws + off; off += (size_t)N * 128;  // h1bf uses N*64 uints; spare upper half hosts binned
    float* out1 = ws + off; off += (size_t)N * 128;   // out1b uses N*64 uints (bf16)
    float* as1  = ws + off; off += (size_t)N * 4;
    float* ad1  = ws + off; off += (size_t)N * 4;
    float* as2  = ws + off; off += (size_t)N;
    float* ad2  = ws + off; off += (size_t)N;
    int* rowptr    = (int*)(ws + off); off += (size_t)N + 4;
    int* bucketptr = (int*)(ws + off); off += 1024;   // NB+1 <= 513
    int* bhist     = (int*)(ws + off); off += 512;
    int* bcursor   = (int*)(ws + off); off += 512;
    int* colarr    = (int*)(ws + off); off += (size_t)T;
    unsigned* h1bf = (unsigned*)h1reg;                       // N*64 uints (bf16x2)
    unsigned* h2bf = (unsigned*)h1reg;                       // reuses h1reg after gather1
    unsigned* out1b = (unsigned*)out1;                       // N*64 uints (bf16x2)
    unsigned* binned = (unsigned*)h1reg + (size_t)N * 64;    // T uints in h1reg's spare half

    const int B = 256;
    auto blocks = [](size_t t, int b) { return (unsigned)((t + b - 1) / b); };

    // bucket-binned CSR build
    hipMemsetAsync(bhist, 0, 512 * sizeof(int), stream);
    k_binhist<<<256, 256, 0, stream>>>(ei, bhist, E, N);
    k_binscan<<<1, 512, 0, stream>>>(bhist, bucketptr, bcursor, rowptr, NB, N, T);
    k_binfill<<<blocks(T, BF_CHUNK), 512, 0, stream>>>(ei, bcursor, binned, E, N);

    // fat kernel: bucketfill (CSR tail) + gemm1 (independent) overlapped
    k_bucketfill_gemm1<<<(unsigned)(NB + (N + 31) / 32), B, 0, stream>>>(
        binned, bucketptr, rowptr, colarr,
        x, W1, a_src1, a_dst1, h1bf, as1, ad1, N, NB);

    // layer 1 gather (two-pass, 8 edges/iter; bf16 out1)
    k_gather1<<<(unsigned)((N + 3) / 4), B, 0, stream>>>(rowptr, colarr, as1, ad1, h1bf, b1, out1b, N);

    // layer 2 (+ fused final linear)
    k_gemm2  <<<(unsigned)((N + 127) / 128), B, 0, stream>>>(out1b, W2, a_src2, a_dst2, h2bf, as2, ad2, N);
    k_gather2<<<blocks((size_t)N * 32, B), B, 0, stream>>>(rowptr, colarr, as2, ad2,
                                                           h2bf, b2, W_lin, b_lin, out, N);
}